// Round 10
// baseline (765.140 us; speedup 1.0000x reference)
//
#include <hip/hip_runtime.h>
#include <hip/hip_bf16.h>
#include <math.h>

#define LYR   2
#define H     512
#define NH    32
#define BATCH 8
#define SEQL  4096
#define QC    64
#define NC    (SEQL / QC)
#define MROWS (BATCH * SEQL)

typedef __attribute__((ext_vector_type(8))) short short8;
typedef __attribute__((ext_vector_type(4))) float floatx4;
typedef __hip_bfloat16 bf16;

__device__ __forceinline__ float gelu_f(float x) {
    return 0.5f * x * (1.0f + erff(x * 0.70710678118654752440f));
}

__device__ __forceinline__ void glds16(const void* g, void* l) {
    __builtin_amdgcn_global_load_lds((const __attribute__((address_space(1))) void*)g,
                                     (__attribute__((address_space(3))) void*)l, 16, 0, 0);
}

// ---------------------------------------------------------------------------
// Weight cast + transpose: W[l][k][n] fp32 -> Wt[l][n][k] bf16
// Optionally also emits the straight (non-transposed) bf16 copy into Wf.
// ---------------------------------------------------------------------------
__global__ void cast_w_kernel(const float* __restrict__ W, bf16* __restrict__ Wt,
                              bf16* __restrict__ Wf) {
    __shared__ __align__(16) float tile[64][65];
    const int l  = blockIdx.z;
    const int k0 = blockIdx.y * 64;
    const int n0 = blockIdx.x * 64;
    const float* src = W + (size_t)l * H * H;
    bf16* dst = Wt + (size_t)l * H * H;
    bf16* dstf = Wf ? (Wf + (size_t)l * H * H) : nullptr;
#pragma unroll
    for (int i = 0; i < 16; i++) {
        int e = i * 256 + threadIdx.x;
        int r = e >> 6, c = e & 63;
        const float v = src[(size_t)(k0 + r) * H + n0 + c];
        tile[r][c] = v;
        if (dstf) dstf[(size_t)(k0 + r) * H + n0 + c] = __float2bfloat16(v);
    }
    __syncthreads();
#pragma unroll
    for (int i = 0; i < 16; i++) {
        int e = i * 256 + threadIdx.x;
        int r = e >> 6, c = e & 63;
        dst[(size_t)(n0 + r) * H + k0 + c] = __float2bfloat16(tile[c][r]);
    }
}

// ---------------------------------------------------------------------------
// Wct[l][n][m] = sum_k W1t[l][n][k] * Wkf[l][m][k]  ( = (Wk@W1)^T, bf16 )
// ---------------------------------------------------------------------------
__global__ void wc_gemm(const bf16* __restrict__ W1t, const bf16* __restrict__ Wkf,
                        bf16* __restrict__ Wct) {
    const int l  = blockIdx.z;
    const int n0 = blockIdx.y * 64;
    const int m0 = blockIdx.x * 64;
    const bf16* A = W1t + (size_t)l * H * H;   // [n][k]
    const bf16* B = Wkf + (size_t)l * H * H;   // [m][k]
    bf16* O = Wct + (size_t)l * H * H;         // [n][m]
    __shared__ __align__(16) bf16 As[64][72];
    __shared__ __align__(16) bf16 Bs[64][72];
    const int tid = threadIdx.x, lane = tid & 63, wid = tid >> 6;
    const int wn = (wid >> 1) * 32, wm = (wid & 1) * 32;
    floatx4 acc[2][2] = {};
    for (int kk = 0; kk < 512; kk += 64) {
#pragma unroll
        for (int i = 0; i < 2; i++) {
            int idx = i * 256 + tid, r = idx >> 3, c8 = (idx & 7) * 8;
            *(floatx4*)&As[r][c8] = *(const floatx4*)(A + (size_t)(n0 + r) * 512 + kk + c8);
            *(floatx4*)&Bs[r][c8] = *(const floatx4*)(B + (size_t)(m0 + r) * 512 + kk + c8);
        }
        __syncthreads();
#pragma unroll
        for (int ks = 0; ks < 64; ks += 32) {
            short8 af[2], bfr[2];
#pragma unroll
            for (int mt = 0; mt < 2; mt++)
                af[mt] = *(const short8*)&As[wn + mt * 16 + (lane & 15)][ks + (lane >> 4) * 8];
#pragma unroll
            for (int nt = 0; nt < 2; nt++)
                bfr[nt] = *(const short8*)&Bs[wm + nt * 16 + (lane & 15)][ks + (lane >> 4) * 8];
#pragma unroll
            for (int mt = 0; mt < 2; mt++)
#pragma unroll
                for (int nt = 0; nt < 2; nt++)
                    acc[mt][nt] = __builtin_amdgcn_mfma_f32_16x16x32_bf16(
                        af[mt], bfr[nt], acc[mt][nt], 0, 0, 0);
        }
        __syncthreads();
    }
#pragma unroll
    for (int mt = 0; mt < 2; mt++)
#pragma unroll
        for (int nt = 0; nt < 2; nt++) {
            const int col = m0 + wm + nt * 16 + (lane & 15);
#pragma unroll
            for (int r = 0; r < 4; r++) {
                const int row = n0 + wn + mt * 16 + ((lane >> 4) << 2) + r;
                O[(size_t)row * 512 + col] = __float2bfloat16(acc[mt][nt][r]);
            }
        }
}

// ---------------------------------------------------------------------------
// bc[l][n] = b1[l][n] + sum_k bk[l][k] * W1[l][k][n]
// ---------------------------------------------------------------------------
__global__ void bias_comb_kernel(const float* __restrict__ bk, const float* __restrict__ W1,
                                 const float* __restrict__ b1, float* __restrict__ bc) {
    const int l  = blockIdx.y;
    const int n  = blockIdx.x * 64 + (threadIdx.x & 63);
    const int kq = threadIdx.x >> 6;
    float s = 0.f;
    for (int k = kq * 128; k < kq * 128 + 128; k++)
        s += bk[l * H + k] * W1[((size_t)l * H + k) * H + n];
    __shared__ float red[4][64];
    red[kq][threadIdx.x & 63] = s;
    __syncthreads();
    if (threadIdx.x < 64) {
        bc[l * H + n] = red[0][threadIdx.x] + red[1][threadIdx.x] +
                        red[2][threadIdx.x] + red[3][threadIdx.x] + b1[l * H + n];
    }
}

// ---------------------------------------------------------------------------
// SSM discretization: dtA = dt*A, coef = C*B*(exp(dtA)-1)/A, dAQ = exp(dtA)^QC
// ---------------------------------------------------------------------------
__global__ void ssm_params_kernel(const float* __restrict__ log_dt,
                                  const float* __restrict__ A_re, const float* __restrict__ A_im,
                                  const float* __restrict__ B_re, const float* __restrict__ B_im,
                                  const float* __restrict__ C_re, const float* __restrict__ C_im,
                                  float* __restrict__ dtA, float* __restrict__ coef,
                                  float* __restrict__ dAQ) {
    const int idx = blockIdx.x * 256 + threadIdx.x;
    if (idx >= LYR * H * NH) return;
    const int lh = idx >> 5;
    const float dt  = expf(log_dt[lh]);
    const float are = A_re[idx], aim = A_im[idx];
    const float e   = expf(dt * are);
    const float dre = e * cosf(dt * aim);
    const float dim_ = e * sinf(dt * aim);
    const float den = are * are + aim * aim;
    const float nre = dre - 1.0f, nim = dim_;
    const float qre = (nre * are + nim * aim) / den;
    const float qim = (nim * are - nre * aim) / den;
    const float bre = B_re[idx], bim = B_im[idx];
    const float dbre = bre * qre - bim * qim;
    const float dbim = bre * qim + bim * qre;
    const float cre = C_re[idx], cim = C_im[idx];
    coef[2 * idx]     = cre * dbre - cim * dbim;
    coef[2 * idx + 1] = cre * dbim + cim * dbre;
    dtA[2 * idx]     = dt * are;
    dtA[2 * idx + 1] = dt * aim;
    const float eq = expf((float)QC * dt * are);
    const float ph = (float)QC * dt * aim;
    dAQ[2 * idx]     = eq * cosf(ph);
    dAQ[2 * idx + 1] = eq * sinf(ph);
}

// ---------------------------------------------------------------------------
// Build per-(l,h) conv matrices — closed-form powers, fully parallel.
// ---------------------------------------------------------------------------
__global__ void prep_mats(const float* __restrict__ dtA, const float* __restrict__ coef,
                          const float* __restrict__ Dv,
                          bf16* __restrict__ M1b, bf16* __restrict__ TEb) {
    const int lh  = blockIdx.x;
    const int tid = threadIdx.x;
    const int t   = tid >> 2;
    const int ng  = tid & 3;
    __shared__ float Ksh[64];
    __shared__ __align__(16) bf16 TE[64][192];
    __shared__ __align__(16) bf16 M1s[64][64];

    const float ft = (float)t;
    float Kt = 0.f;
#pragma unroll
    for (int k = 0; k < 8; k++) {
        const int n = ng * 8 + k;
        const float dtr = dtA[((size_t)lh * NH + n) * 2];
        const float dti = dtA[((size_t)lh * NH + n) * 2 + 1];
        const float cre = coef[((size_t)lh * NH + n) * 2];
        const float cim = coef[((size_t)lh * NH + n) * 2 + 1];
        const float er  = expf(dtr);
        const float dre = er * cosf(dti), dim_ = er * sinf(dti);
        const float et = expf(ft * dtr);
        const float pr = et * cosf(ft * dti), pi = et * sinf(ft * dti);
        Kt = fmaf(2.f * cre, pr, fmaf(-2.f * cim, pi, Kt));
        const float per = pr * dre - pi * dim_;
        const float pei = pr * dim_ + pi * dre;
        const float e0 = 2.f * (cre * per - cim * pei);
        const float e1 = -2.f * (cre * pei + cim * per);
        const bf16 b0 = __float2bfloat16(e0), b1 = __float2bfloat16(e1);
        TE[t][64 + 2 * n]  = b0;
        TE[t][65 + 2 * n]  = b1;
        TE[t][128 + 2 * n] = b0;
        TE[t][129 + 2 * n] = b1;
        const float fq = (float)(63 - t);
        const float eq = expf(fq * dtr);
        const float qr = eq * cosf(fq * dti), qi = eq * sinf(fq * dti);
        M1s[2 * n][t]     = __float2bfloat16(qr);
        M1s[2 * n + 1][t] = __float2bfloat16(qi);
    }
    Kt += __shfl_xor(Kt, 1);
    Kt += __shfl_xor(Kt, 2);
    if (ng == 0) Ksh[t] = Kt;
    __syncthreads();
    const float Dh = Dv[lh];
#pragma unroll
    for (int i = 0; i < 16; i++) {
        const int tau = ng * 16 + i;
        float v = (tau > t) ? 0.f : Ksh[t - tau];
        if (tau == t) v += Dh;
        TE[t][tau] = __float2bfloat16(v);
    }
    __syncthreads();
    bf16* tep = TEb + (size_t)lh * 64 * 192;
    const bf16* tes = &TE[0][0];
#pragma unroll
    for (int i = 0; i < 6; i++) {
        const int idx = i * 256 + tid;
        *(floatx4*)(tep + (size_t)idx * 8) = *(const floatx4*)(tes + (size_t)idx * 8);
    }
    bf16* m1p = M1b + (size_t)lh * 64 * 64;
    const bf16* m1s = &M1s[0][0];
#pragma unroll
    for (int i = 0; i < 2; i++) {
        const int idx = i * 256 + tid;
        *(floatx4*)(m1p + (size_t)idx * 8) = *(const floatx4*)(m1s + (size_t)idx * 8);
    }
}

// ---------------------------------------------------------------------------
// LayerNorm over H=512 on BF16 input (o1), fp32 stats, bf16 out (LN2).
// ---------------------------------------------------------------------------
__global__ void ln_bf16_kernel(const bf16* __restrict__ src,
                               const float* __restrict__ gamma, const float* __restrict__ beta,
                               bf16* __restrict__ outb) {
    const int lane = threadIdx.x & 63;
    const int row  = blockIdx.x * 4 + (threadIdx.x >> 6);
    const ushort* rp = (const ushort*)(src + (size_t)row * H);
    short8 v = *(const short8*)(rp + lane * 8);
    float f[8];
#pragma unroll
    for (int j = 0; j < 8; j++)
        f[j] = __uint_as_float(((unsigned)(ushort)v[j]) << 16);
    float s = 0.f, q = 0.f;
#pragma unroll
    for (int j = 0; j < 8; j++) { s += f[j]; q += f[j] * f[j]; }
#pragma unroll
    for (int off = 32; off > 0; off >>= 1) {
        s += __shfl_xor(s, off);
        q += __shfl_xor(q, off);
    }
    const float mean = s * (1.0f / H);
    const float var  = q * (1.0f / H) - mean * mean;
    const float rstd = rsqrtf(var + 1e-5f);
    const float4* gp = (const float4*)gamma;
    const float4* bp = (const float4*)beta;
    const float4 g0 = gp[lane * 2], g1 = gp[lane * 2 + 1];
    const float4 b0 = bp[lane * 2], b1 = bp[lane * 2 + 1];
    const float gg[8] = {g0.x, g0.y, g0.z, g0.w, g1.x, g1.y, g1.z, g1.w};
    const float bb[8] = {b0.x, b0.y, b0.z, b0.w, b1.x, b1.y, b1.z, b1.w};
    __align__(16) ushort t[8];
#pragma unroll
    for (int j = 0; j < 8; j++) {
        bf16 h = __float2bfloat16((f[j] - mean) * rstd * gg[j] + bb[j]);
        t[j] = *reinterpret_cast<ushort*>(&h);
    }
    *(floatx4*)((ushort*)outb + (size_t)row * H + lane * 8) = *(const floatx4*)t;
}

// ---------------------------------------------------------------------------
// Fused LN1 + transpose: cur[b,t,h] fp32 -> LN -> bf16 -> Ub[h][bc][tau]
// ---------------------------------------------------------------------------
__global__ __launch_bounds__(512) void ln_trans_k(const float* __restrict__ src,
                                                  const float* __restrict__ gamma,
                                                  const float* __restrict__ beta,
                                                  bf16* __restrict__ Ub) {
    __shared__ __align__(16) ushort Z[64][516];   // pad 4: row stride 1032 B, 8B-aligned
    const int bc   = blockIdx.x;
    const int tid  = threadIdx.x;
    const int lane = tid & 63;
    const int wv   = tid >> 6;                    // 0..7
    const float4* gp = (const float4*)gamma;
    const float4* bp = (const float4*)beta;
    const float4 g0 = gp[lane], g1 = gp[64 + lane];
    const float4 b0 = bp[lane], b1 = bp[64 + lane];
#pragma unroll
    for (int i = 0; i < 8; i++) {
        const int tau = wv * 8 + i;
        const float4* rp = (const float4*)(src + ((size_t)bc * 64 + tau) * H);
        const float4 v0 = rp[lane];
        const float4 v1 = rp[64 + lane];
        float s = v0.x + v0.y + v0.z + v0.w + v1.x + v1.y + v1.z + v1.w;
        float q = v0.x * v0.x + v0.y * v0.y + v0.z * v0.z + v0.w * v0.w +
                  v1.x * v1.x + v1.y * v1.y + v1.z * v1.z + v1.w * v1.w;
#pragma unroll
        for (int off = 32; off > 0; off >>= 1) {
            s += __shfl_xor(s, off);
            q += __shfl_xor(q, off);
        }
        const float mean = s * (1.0f / H);
        const float var  = q * (1.0f / H) - mean * mean;
        const float rstd = rsqrtf(var + 1e-5f);
        bf16 t0[4] = {__float2bfloat16((v0.x - mean) * rstd * g0.x + b0.x),
                      __float2bfloat16((v0.y - mean) * rstd * g0.y + b0.y),
                      __float2bfloat16((v0.z - mean) * rstd * g0.z + b0.z),
                      __float2bfloat16((v0.w - mean) * rstd * g0.w + b0.w)};
        bf16 t1[4] = {__float2bfloat16((v1.x - mean) * rstd * g1.x + b1.x),
                      __float2bfloat16((v1.y - mean) * rstd * g1.y + b1.y),
                      __float2bfloat16((v1.z - mean) * rstd * g1.z + b1.z),
                      __float2bfloat16((v1.w - mean) * rstd * g1.w + b1.w)};
        *(uint2*)&Z[tau][lane * 4]       = *(uint2*)t0;
        *(uint2*)&Z[tau][256 + lane * 4] = *(uint2*)t1;
    }
    __syncthreads();
#pragma unroll
    for (int hb = 0; hb < 8; hb++) {
        ushort* up = (ushort*)Ub + ((size_t)(hb * 64) * 512 + bc) * 64;
#pragma unroll
        for (int i = 0; i < 2; i++) {
            const int hh = i * 32 + (tid >> 4);
            const int t4 = (tid & 15) * 4;
            const int hc = hb * 64 + hh;
            ushort4 v;
            v.x = Z[t4][hc]; v.y = Z[t4 + 1][hc]; v.z = Z[t4 + 2][hc]; v.w = Z[t4 + 3][hc];
            *(ushort4*)(up + (size_t)hh * 512 * 64 + t4) = v;
        }
    }
}

// ---------------------------------------------------------------------------
// FUSED conv phase 1 + chunk scan (proven round-9).
// ---------------------------------------------------------------------------
__global__ void conv_p1s(const bf16* __restrict__ M1l, const bf16* __restrict__ Ub,
                         const float* __restrict__ dAQl, bf16* __restrict__ S0b) {
    const int h = blockIdx.x >> 2;
    const int n0 = (blockIdx.x & 3) * 128;
    __shared__ __align__(16) char sm[33024 + 34816];
    bf16(*As)[72] = (bf16(*)[72])sm;                      //  9,216 B
    bf16(*Bs)[72] = (bf16(*)[72])(sm + 9216);             // 18,432 B (ends 27,648)
    float(*Sl)[129] = (float(*)[129])sm;                  // 33,024 B (after MFMA, As/Bs dead)
    bf16(*Ob)[136] = (bf16(*)[136])(sm + 33024);          // 34,816 B
    const int tid = threadIdx.x, lane = tid & 63, wid = tid >> 6;
    const int wm = (wid & 1) * 32, wn = (wid >> 1) * 64;
#pragma unroll
    for (int i = 0; i < 2; i++) {
        int idx = i * 256 + tid, r = idx >> 3, c8 = (idx & 7) * 8;
        *(floatx4*)&As[r][c8] = *(const floatx4*)(M1l + ((size_t)h * 64 + r) * 64 + c8);
    }
#pragma unroll
    for (int i = 0; i < 4; i++) {
        int idx = i * 256 + tid, r = idx >> 3, c8 = (idx & 7) * 8;
        *(floatx4*)&Bs[r][c8] = *(const floatx4*)(Ub + ((size_t)h * 512 + n0 + r) * 64 + c8);
    }
    __syncthreads();
    floatx4 acc[2][4] = {};
#pragma unroll
    for (int ks = 0; ks < 64; ks += 32) {
        short8 af[2], bfr[4];
#pragma unroll
        for (int mt = 0; mt < 2; mt++)
            af[mt] = *(const short8*)&As[wm + mt * 16 + (lane & 15)][ks + (lane >> 4) * 8];
#pragma unroll
        for (int nt = 0; nt < 4; nt++)
            bfr[nt] = *(const short8*)&Bs[wn + nt * 16 + (lane & 15)][ks + (lane >> 4) * 8];
#pragma unroll
        for (int mt = 0; mt < 2; mt++)
#pragma unroll
            for (int nt = 0; nt < 4; nt++)
                acc[mt][nt] = __builtin_amdgcn_mfma_f32_16x16x32_bf16(af[mt], bfr[nt], acc[mt][nt], 0, 0, 0);
    }
    __syncthreads();                                 // As/Bs reads done everywhere
#pragma unroll
    for (int mt = 0; mt < 2; mt++)
#pragma unroll
        for (int nt = 0; nt < 4; nt++) {
            const int bcl = wn + nt * 16 + (lane & 15);       // local bc 0..127
#pragma unroll
            for (int r = 0; r < 4; r++) {
                const int j = wm + mt * 16 + ((lane >> 4) << 2) + r;
                Sl[j][bcl] = acc[mt][nt][r];
            }
        }
    __syncthreads();
    // scan: 64 chains = 32 complex states x 2 batches, each serial over 64 chunks
    if (tid < 64) {
        const int n = tid & 31;
        const int b = tid >> 5;                      // 0..1 (local)
        const float qr = dAQl[(h * NH + n) * 2], qi = dAQl[(h * NH + n) * 2 + 1];
        float rr = 0.f, ri = 0.f;
        for (int c = 0; c < 64; c++) {
            const int bcl = b * 64 + c;
            bf16 hr = __float2bfloat16(rr);
            bf16 hi = __float2bfloat16(ri);
            Ob[bcl][2 * n]          = hr;
            Ob[bcl][2 * n + 1]      = hi;
            Ob[bcl][64 + 2 * n]     = __float2bfloat16(rr - __bfloat162float(hr));
            Ob[bcl][64 + 2 * n + 1] = __float2bfloat16(ri - __bfloat162float(hi));
            const float lr = Sl[2 * n][bcl], li = Sl[2 * n + 1][bcl];
            const float tr = qr * rr - qi * ri + lr;
            ri = qr * ri + qi * rr + li;
            rr = tr;
        }
    }
    __syncthreads();
    bf16* op = S0b + ((size_t)h * 512 + n0) * 128;
#pragma unroll
    for (int i = 0; i < 8; i++) {
        int idx = i * 256 + tid, row = idx >> 4, c8 = (idx & 15) * 8;
        *(floatx4*)(op + (size_t)row * 128 + c8) = *(const floatx4*)&Ob[row][c8];
    }
}

// ---------------------------------------------------------------------------
// Conv phase 3, DE-STAGED: operands read directly from global (the layouts
// TEl[t][192], Ub[bc][64], S0b[bc][128] are already MFMA [row][k] fragment
// layouts, 16B-aligned; per-byte reuse inside a block is only 2x -> L1/L2
// serves it).  LDS only holds the 128x72 output-transpose tile (18.4 KB ->
// up to 8 blocks/CU vs round-9's 2).  Kills the 1.84M bank conflicts from
// the Bs stride-400B reads.  MFMA k-order/values identical -> bit-identical.
// ---------------------------------------------------------------------------
__global__ void conv_p3(const bf16* __restrict__ TEl, const bf16* __restrict__ Ub,
                        const bf16* __restrict__ S0b, bf16* __restrict__ Yt) {
    const int h = blockIdx.x >> 2;
    const int n0 = (blockIdx.x & 3) * 128;
    __shared__ __align__(16) bf16 Tt[128][72];    // 18,432 B
    const int tid = threadIdx.x, lane = tid & 63, wid = tid >> 6;
    const int wm = (wid & 1) * 32, wn = (wid >> 1) * 64;
    const bf16* tep = TEl + (size_t)h * 64 * 192;
    const bf16* up  = Ub  + ((size_t)h * 512 + n0) * 64;
    const bf16* sp  = S0b + ((size_t)h * 512 + n0) * 128;
    floatx4 acc[2][4] = {};
#pragma unroll
    for (int ks = 0; ks < 192; ks += 32) {
        const int ko = ks + (lane >> 4) * 8;
        short8 af[2], bfr[4];
#pragma unroll
        for (int mt = 0; mt < 2; mt++)
            af[mt] = *(const short8*)(tep + (size_t)(wm + mt * 16 + (lane & 15)) * 192 + ko);
#pragma unroll
        for (int nt = 0; nt < 4; nt++) {
            const int row = wn + nt * 16 + (lane & 15);
            if (ks < 64)
                bfr[nt] = *(const short8*)(up + (size_t)row * 64 + ko);
            else
                bfr[nt] = *(const short8*)(sp + (size_t)row * 128 + (ko - 64));
        }
#pragma unroll
        for (int mt = 0; mt < 2; mt++)
#pragma unroll
            for (int nt = 0; nt < 4; nt++)
                acc[mt][nt] = __builtin_amdgcn_mfma_f32_16x16x32_bf16(af[mt], bfr[nt], acc[mt][nt], 0, 0, 0);
    }
#pragma unroll
    for (int mt = 0; mt < 2; mt++)
#pragma unroll
        for (int nt = 0; nt < 4; nt++) {
            const int n = wn + nt * 16 + (lane & 15);
#pragma unroll
            for (int r = 0; r < 4; r++) {
                const int t = wm + mt * 16 + ((lane >> 4) << 2) + r;
                Tt[n][t] = __float2bfloat16(gelu_f(acc[mt][nt][r]));
            }
        }
    __syncthreads();
#pragma unroll
    for (int i = 0; i < 4; i++) {
        int idx = i * 256 + tid, r = idx >> 3, c8 = (idx & 7) * 8;
        *(floatx4*)(Yt + ((size_t)h * 512 + n0 + r) * 64 + c8) = *(const floatx4*)&Tt[r][c8];
    }
}

// ---------------------------------------------------------------------------
// Transpose Yt[h][bc][t] -> y[b, c*64+t, h] bf16
// ---------------------------------------------------------------------------
__global__ void trans_out_k(const bf16* __restrict__ Yt, bf16* __restrict__ y) {
    const int hb = blockIdx.x & 7, bc = blockIdx.x >> 3;
    const int b = bc >> 6, c = bc & 63;
    const int h0 = hb * 64;
    __shared__ __align__(16) ushort Ti[64][68];
    const ushort* yp = (const ushort*)Yt + ((size_t)h0 * 512 + bc) * 64;
#pragma unroll
    for (int i = 0; i < 4; i++) {
        int hh = i * 16 + (threadIdx.x >> 4), t4 = (threadIdx.x & 15) * 4;
        *(ushort4*)&Ti[hh][t4] = *(const ushort4*)(yp + (size_t)hh * 512 * 64 + t4);
    }
    __syncthreads();
    ushort* op = (ushort*)y + ((size_t)b * SEQL + c * QC) * H + h0;
#pragma unroll
    for (int i = 0; i < 4; i++) {
        int tau = i * 16 + (threadIdx.x >> 4), h4 = (threadIdx.x & 15) * 4;
        ushort4 v;
        v.x = Ti[h4][tau]; v.y = Ti[h4 + 1][tau]; v.z = Ti[h4 + 2][tau]; v.w = Ti[h4 + 3][tau];
        *(ushort4*)(op + (size_t)tau * H + h4) = v;
    }
}

// ---------------------------------------------------------------------------
// bf16 MFMA GEMM with global_load_lds(16B) staging + XOR-swizzled LDS.
// PROVEN single-buffer structure (32 KB LDS) + bijective XCD swizzle.
// GEMM sync structure is frozen (r2/r7 pipeline attempts both regressed).
// ---------------------------------------------------------------------------
enum { M_BIAS = 0, M_RES = 1, M_GELU = 2, M_DUAL = 3 };

template <int MODE>
__global__ void gemm_kernel(const bf16* __restrict__ A1, const bf16* __restrict__ Wt1,
                            const bf16* __restrict__ A2, const bf16* __restrict__ Wt2,
                            const float* __restrict__ bias1, const float* __restrict__ bias2,
                            const float* __restrict__ res,
                            float* __restrict__ outf, bf16* __restrict__ outb, int KTOT) {
    __shared__ __align__(16) bf16 As[128][64];
    __shared__ __align__(16) bf16 Bs[128][64];
    const int tid  = threadIdx.x;
    const int lane = tid & 63;
    const int wid  = tid >> 6;
    const int wm   = (wid >> 1) * 64;
    const int wn   = (wid & 1) * 64;
    const int id   = blockIdx.y * 4 + blockIdx.x;
    const int q    = gridDim.y >> 1;              // nwg/8; nwg % 8 == 0 always
    const int nid  = (id & 7) * q + (id >> 3);
    const int m0   = (nid >> 2) * 128;
    const int n0   = (nid & 3) * 128;

    floatx4 acc[4][4] = {};

    for (int k0 = 0; k0 < KTOT; k0 += 64) {
        const bf16* Ap;
        const bf16* Wp;
        int kk = k0;
        if (MODE == M_DUAL && k0 >= 512) { Ap = A2; Wp = Wt2; kk = k0 - 512; }
        else                             { Ap = A1; Wp = Wt1; }
#pragma unroll
        for (int i = 0; i < 4; i++) {
            const int s   = wid * 256 + i * 64 + lane;   // 16B slot index
            const int r   = s >> 3;
            const int cbg = (s & 7) ^ (r & 7);           // swizzled source col-block
            glds16(Ap + (size_t)(m0 + r) * 512 + kk + cbg * 8,
                   (char*)&As[0][0] + (size_t)(wid * 256 + i * 64) * 16);
            glds16(Wp + (size_t)(n0 + r) * 512 + kk + cbg * 8,
                   (char*)&Bs[0][0] + (size_t)(wid * 256 + i * 64) * 16);
        }
        __syncthreads();
#pragma unroll
        for (int ks = 0; ks < 64; ks += 32) {
            short8 af[4], bfr[4];
#pragma unroll
            for (int mt = 0; mt < 4; mt++) {
                const int row = wm + mt * 16 + (lane & 15);
                const int cph = ((ks >> 3) + (lane >> 4)) ^ (row & 7);
                af[mt] = *(const short8*)&As[row][cph * 8];
            }
#pragma unroll
            for (int nt = 0; nt < 4; nt++) {
                const int row = wn + nt * 16 + (lane & 15);
                const int cph = ((ks >> 3) + (lane >> 4)) ^ (row & 7);
                bfr[nt] = *(const short8*)&Bs[row][cph * 8];
            }
#pragma unroll
            for (int mt = 0; mt < 4; mt++)
#pragma unroll
                for (int nt = 0; nt < 4; nt++)
                    acc[mt][nt] = __builtin_amdgcn_mfma_f32_16x16x32_bf16(
                        af[mt], bfr[nt], acc[mt][nt], 0, 0, 0);
        }
        __syncthreads();
    }

#pragma unroll
    for (int mt = 0; mt < 4; mt++) {
        const int rbase = m0 + wm + mt * 16 + ((lane >> 4) << 2);
#pragma unroll
        for (int nt = 0; nt < 4; nt++) {
            const int col = n0 + wn + nt * 16 + (lane & 15);
            float bsum = bias1 ? bias1[col] : 0.0f;
            if constexpr (MODE == M_DUAL) bsum += bias2[col];
#pragma unroll
            for (int r = 0; r < 4; r++) {
                const int row = rbase + r;
                float v = acc[mt][nt][r] + bsum;
                if constexpr (MODE == M_RES) v += res[(size_t)row * H + col];
                if constexpr (MODE == M_GELU) v = gelu_f(v);
                const size_t o = (size_t)row * H + col;
                if constexpr (MODE == M_DUAL) outf[o] = v;
                else                          outb[o] = __float2bfloat16(v);
            }
        }
    }
}

// ---------------------------------------------------------------------------
extern "C" void kernel_launch(void* const* d_in, const int* in_sizes, int n_in,
                              void* d_out, int out_size, void* d_ws, size_t ws_size,
                              hipStream_t stream) {
    const float* x     = (const float*)d_in[0];
    const float* ln1w  = (const float*)d_in[1];
    const float* ln1b  = (const float*)d_in[2];
    const float* ln2w  = (const float*)d_in[3];
    const float* ln2b  = (const float*)d_in[4];
    const float* logdt = (const float*)d_in[5];
    const float* Are   = (const float*)d_in[6];
    const float* Aim   = (const float*)d_in[7];
    const float* Bre   = (const float*)d_in[8];
    const float* Bim   = (const float*)d_in[9];
    const float* Cre   = (const float*)d_in[10];
    const float* Cim   = (const float*)d_in[11];
    const float* Dvec  = (const float*)d_in[12];
    const float* Wk    = (const float*)d_in[13];
    const float* bk    = (const float*)d_in[14];
    const float* W1    = (const float*)d_in[15];
    const float* b1    = (const float*)d_in[16];
    const float* W2    = (const float*)d_in[17];
    const float* b2    = (const float*)d_in[18];
    const float* Wout  = (const float*)d_in[19];
    const float* bout  = (const float*)d_in[20];
    const float* Wproj = (const float*)d_in[21];
    const float* bproj = (const float*)d_in[22];
    float* outp = (float*)d_out;

    char* p = (char*)d_ws;
    auto carve = [&](size_t bytes) -> char* {
        char* r = p;
        p += (bytes + 255) & ~(size_t)255;
        return r;
    };
    bf16*  zbA  = (bf16*)carve((size_t)MROWS * H * 2);
    bf16*  Ub   = (bf16*)carve((size_t)H * 512 * 64 * 2);
    bf16*  S0b  = (bf16*)carve((size_t)H * 512 * 128 * 2);
    bf16*  M1b  = (bf16*)carve((size_t)LYR * H * 64 * 64 * 2);
    bf16*  TEb  = (bf16*)carve((size_t)LYR * H * 64 * 192 * 2);
    float* dtAb = (float*)carve((size_t)LYR * H * NH * 2 * 4);
    float* cfb  = (float*)carve((size_t)LYR * H * NH * 2 * 4);
    float* dAQb = (float*)carve((size_t)LYR * H * NH * 2 * 4);
    bf16* wts[5];
    for (int i = 0; i < 5; i++) wts[i] = (bf16*)carve((size_t)LYR * H * H * 2);
    bf16*  Wkf = (bf16*)carve((size_t)LYR * H * H * 2);   // Wk straight bf16
    float* bcb = (float*)carve((size_t)LYR * H * 4);      // combined bias

    bf16*  Yt   = zbA;
    bf16*  bb1  = Ub;                               // Ub dead after conv_p3
    bf16*  bb0  = S0b;                              // S0b dead after conv_p3
    bf16*  bb2  = S0b + (size_t)MROWS * H;          // second half of S0b

    const float* wsrc[5] = {Wk, W1, W2, Wout, Wproj};
    {
        dim3 g(8, 8, LYR);
        for (int i = 0; i < 5; i++)
            cast_w_kernel<<<g, 256, 0, stream>>>(wsrc[i], wts[i], i == 0 ? Wkf : nullptr);
    }
    // Collapse Wk@W1 -> Wct (into wts[0]): Wct[n][m] = sum_k W1t[n][k]*Wkf[m][k]
    wc_gemm<<<dim3(8, 8, LYR), 256, 0, stream>>>(wts[1], Wkf, wts[0]);
    bias_comb_kernel<<<dim3(8, LYR), 256, 0, stream>>>(bk, W1, b1, bcb);

    ssm_params_kernel<<<(LYR * H * NH) / 256, 256, 0, stream>>>(
        logdt, Are, Aim, Bre, Bim, Cre, Cim, dtAb, cfb, dAQb);
    prep_mats<<<LYR * H, 256, 0, stream>>>(dtAb, cfb, Dvec, M1b, TEb);

    const float* cur = x;
    for (int l = 0; l < LYR; l++) {
        ln_trans_k<<<MROWS / 64, 512, 0, stream>>>(cur, ln1w + l * H, ln1b + l * H, Ub);
        conv_p1s<<<H * 4, 256, 0, stream>>>(M1b + (size_t)l * H * 64 * 64, Ub,
                                            dAQb + (size_t)l * H * NH * 2, S0b);
        conv_p3<<<H * 4, 256, 0, stream>>>(TEb + (size_t)l * H * 64 * 192, Ub, S0b, Yt);
        trans_out_k<<<BATCH * NC * 8, 256, 0, stream>>>(Yt, bb0);   // bb0 = y_gelu bf16

        dim3 gg(H / 128, MROWS / 128);
        // o1 = y_gelu @ Wc + bc + out   -> bf16 ONLY (no fp32 round-trip)
        gemm_kernel<M_RES><<<gg, 256, 0, stream>>>(
            bb0, wts[0] + (size_t)l * H * H, nullptr, nullptr,
            bcb + l * H, nullptr, cur, nullptr, bb1, 512);
        // LN2 on bf16 o1 (fp32 stats)
        ln_bf16_kernel<<<MROWS / 4, 256, 0, stream>>>(bb1, ln2w + l * H, ln2b + l * H, bb0);
        gemm_kernel<M_GELU><<<gg, 256, 0, stream>>>(
            bb0, wts[2] + (size_t)l * H * H, nullptr, nullptr,
            b2 + l * H, nullptr, nullptr, nullptr, bb2, 512);
        gemm_kernel<M_DUAL><<<gg, 256, 0, stream>>>(
            bb2, wts[3] + (size_t)l * H * H, bb1, wts[4] + (size_t)l * H * H,
            bout + l * H, bproj + l * H, nullptr, outp, nullptr, 1024);
        cur = outp;
    }
}

// Round 11
// 670.104 us; speedup vs baseline: 1.1418x; 1.1418x over previous
//
#include <hip/hip_runtime.h>
#include <hip/hip_bf16.h>
#include <math.h>

#define LYR   2
#define H     512
#define NH    32
#define BATCH 8
#define SEQL  4096
#define QC    64
#define NC    (SEQL / QC)
#define MROWS (BATCH * SEQL)

typedef __attribute__((ext_vector_type(8))) short short8;
typedef __attribute__((ext_vector_type(4))) float floatx4;
typedef __hip_bfloat16 bf16;

__device__ __forceinline__ float gelu_f(float x) {
    return 0.5f * x * (1.0f + erff(x * 0.70710678118654752440f));
}

__device__ __forceinline__ void glds16(const void* g, void* l) {
    __builtin_amdgcn_global_load_lds((const __attribute__((address_space(1))) void*)g,
                                     (__attribute__((address_space(3))) void*)l, 16, 0, 0);
}

// ---------------------------------------------------------------------------
// Weight cast + transpose: W[l][k][n] fp32 -> Wt[l][n][k] bf16
// Optionally also emits the straight (non-transposed) bf16 copy into Wf.
// ---------------------------------------------------------------------------
__global__ void cast_w_kernel(const float* __restrict__ W, bf16* __restrict__ Wt,
                              bf16* __restrict__ Wf) {
    __shared__ __align__(16) float tile[64][65];
    const int l  = blockIdx.z;
    const int k0 = blockIdx.y * 64;
    const int n0 = blockIdx.x * 64;
    const float* src = W + (size_t)l * H * H;
    bf16* dst = Wt + (size_t)l * H * H;
    bf16* dstf = Wf ? (Wf + (size_t)l * H * H) : nullptr;
#pragma unroll
    for (int i = 0; i < 16; i++) {
        int e = i * 256 + threadIdx.x;
        int r = e >> 6, c = e & 63;
        const float v = src[(size_t)(k0 + r) * H + n0 + c];
        tile[r][c] = v;
        if (dstf) dstf[(size_t)(k0 + r) * H + n0 + c] = __float2bfloat16(v);
    }
    __syncthreads();
#pragma unroll
    for (int i = 0; i < 16; i++) {
        int e = i * 256 + threadIdx.x;
        int r = e >> 6, c = e & 63;
        dst[(size_t)(n0 + r) * H + k0 + c] = __float2bfloat16(tile[c][r]);
    }
}

// ---------------------------------------------------------------------------
// Wct[l][n][m] = sum_k W1t[l][n][k] * Wkf[l][m][k]  ( = (Wk@W1)^T, bf16 )
// ---------------------------------------------------------------------------
__global__ void wc_gemm(const bf16* __restrict__ W1t, const bf16* __restrict__ Wkf,
                        bf16* __restrict__ Wct) {
    const int l  = blockIdx.z;
    const int n0 = blockIdx.y * 64;
    const int m0 = blockIdx.x * 64;
    const bf16* A = W1t + (size_t)l * H * H;   // [n][k]
    const bf16* B = Wkf + (size_t)l * H * H;   // [m][k]
    bf16* O = Wct + (size_t)l * H * H;         // [n][m]
    __shared__ __align__(16) bf16 As[64][72];
    __shared__ __align__(16) bf16 Bs[64][72];
    const int tid = threadIdx.x, lane = tid & 63, wid = tid >> 6;
    const int wn = (wid >> 1) * 32, wm = (wid & 1) * 32;
    floatx4 acc[2][2] = {};
    for (int kk = 0; kk < 512; kk += 64) {
#pragma unroll
        for (int i = 0; i < 2; i++) {
            int idx = i * 256 + tid, r = idx >> 3, c8 = (idx & 7) * 8;
            *(floatx4*)&As[r][c8] = *(const floatx4*)(A + (size_t)(n0 + r) * 512 + kk + c8);
            *(floatx4*)&Bs[r][c8] = *(const floatx4*)(B + (size_t)(m0 + r) * 512 + kk + c8);
        }
        __syncthreads();
#pragma unroll
        for (int ks = 0; ks < 64; ks += 32) {
            short8 af[2], bfr[2];
#pragma unroll
            for (int mt = 0; mt < 2; mt++)
                af[mt] = *(const short8*)&As[wn + mt * 16 + (lane & 15)][ks + (lane >> 4) * 8];
#pragma unroll
            for (int nt = 0; nt < 2; nt++)
                bfr[nt] = *(const short8*)&Bs[wm + nt * 16 + (lane & 15)][ks + (lane >> 4) * 8];
#pragma unroll
            for (int mt = 0; mt < 2; mt++)
#pragma unroll
                for (int nt = 0; nt < 2; nt++)
                    acc[mt][nt] = __builtin_amdgcn_mfma_f32_16x16x32_bf16(
                        af[mt], bfr[nt], acc[mt][nt], 0, 0, 0);
        }
        __syncthreads();
    }
#pragma unroll
    for (int mt = 0; mt < 2; mt++)
#pragma unroll
        for (int nt = 0; nt < 2; nt++) {
            const int col = m0 + wm + nt * 16 + (lane & 15);
#pragma unroll
            for (int r = 0; r < 4; r++) {
                const int row = n0 + wn + mt * 16 + ((lane >> 4) << 2) + r;
                O[(size_t)row * 512 + col] = __float2bfloat16(acc[mt][nt][r]);
            }
        }
}

// ---------------------------------------------------------------------------
// bc[l][n] = b1[l][n] + sum_k bk[l][k] * W1[l][k][n]
// ---------------------------------------------------------------------------
__global__ void bias_comb_kernel(const float* __restrict__ bk, const float* __restrict__ W1,
                                 const float* __restrict__ b1, float* __restrict__ bc) {
    const int l  = blockIdx.y;
    const int n  = blockIdx.x * 64 + (threadIdx.x & 63);
    const int kq = threadIdx.x >> 6;
    float s = 0.f;
    for (int k = kq * 128; k < kq * 128 + 128; k++)
        s += bk[l * H + k] * W1[((size_t)l * H + k) * H + n];
    __shared__ float red[4][64];
    red[kq][threadIdx.x & 63] = s;
    __syncthreads();
    if (threadIdx.x < 64) {
        bc[l * H + n] = red[0][threadIdx.x] + red[1][threadIdx.x] +
                        red[2][threadIdx.x] + red[3][threadIdx.x] + b1[l * H + n];
    }
}

// ---------------------------------------------------------------------------
// SSM discretization: dtA = dt*A, coef = C*B*(exp(dtA)-1)/A, dAQ = exp(dtA)^QC
// ---------------------------------------------------------------------------
__global__ void ssm_params_kernel(const float* __restrict__ log_dt,
                                  const float* __restrict__ A_re, const float* __restrict__ A_im,
                                  const float* __restrict__ B_re, const float* __restrict__ B_im,
                                  const float* __restrict__ C_re, const float* __restrict__ C_im,
                                  float* __restrict__ dtA, float* __restrict__ coef,
                                  float* __restrict__ dAQ) {
    const int idx = blockIdx.x * 256 + threadIdx.x;
    if (idx >= LYR * H * NH) return;
    const int lh = idx >> 5;
    const float dt  = expf(log_dt[lh]);
    const float are = A_re[idx], aim = A_im[idx];
    const float e   = expf(dt * are);
    const float dre = e * cosf(dt * aim);
    const float dim_ = e * sinf(dt * aim);
    const float den = are * are + aim * aim;
    const float nre = dre - 1.0f, nim = dim_;
    const float qre = (nre * are + nim * aim) / den;
    const float qim = (nim * are - nre * aim) / den;
    const float bre = B_re[idx], bim = B_im[idx];
    const float dbre = bre * qre - bim * qim;
    const float dbim = bre * qim + bim * qre;
    const float cre = C_re[idx], cim = C_im[idx];
    coef[2 * idx]     = cre * dbre - cim * dbim;
    coef[2 * idx + 1] = cre * dbim + cim * dbre;
    dtA[2 * idx]     = dt * are;
    dtA[2 * idx + 1] = dt * aim;
    const float eq = expf((float)QC * dt * are);
    const float ph = (float)QC * dt * aim;
    dAQ[2 * idx]     = eq * cosf(ph);
    dAQ[2 * idx + 1] = eq * sinf(ph);
}

// ---------------------------------------------------------------------------
// Build per-(l,h) conv matrices — closed-form powers, fully parallel.
// ---------------------------------------------------------------------------
__global__ void prep_mats(const float* __restrict__ dtA, const float* __restrict__ coef,
                          const float* __restrict__ Dv,
                          bf16* __restrict__ M1b, bf16* __restrict__ TEb) {
    const int lh  = blockIdx.x;
    const int tid = threadIdx.x;
    const int t   = tid >> 2;
    const int ng  = tid & 3;
    __shared__ float Ksh[64];
    __shared__ __align__(16) bf16 TE[64][192];
    __shared__ __align__(16) bf16 M1s[64][64];

    const float ft = (float)t;
    float Kt = 0.f;
#pragma unroll
    for (int k = 0; k < 8; k++) {
        const int n = ng * 8 + k;
        const float dtr = dtA[((size_t)lh * NH + n) * 2];
        const float dti = dtA[((size_t)lh * NH + n) * 2 + 1];
        const float cre = coef[((size_t)lh * NH + n) * 2];
        const float cim = coef[((size_t)lh * NH + n) * 2 + 1];
        const float er  = expf(dtr);
        const float dre = er * cosf(dti), dim_ = er * sinf(dti);
        const float et = expf(ft * dtr);
        const float pr = et * cosf(ft * dti), pi = et * sinf(ft * dti);
        Kt = fmaf(2.f * cre, pr, fmaf(-2.f * cim, pi, Kt));
        const float per = pr * dre - pi * dim_;
        const float pei = pr * dim_ + pi * dre;
        const float e0 = 2.f * (cre * per - cim * pei);
        const float e1 = -2.f * (cre * pei + cim * per);
        const bf16 b0 = __float2bfloat16(e0), b1 = __float2bfloat16(e1);
        TE[t][64 + 2 * n]  = b0;
        TE[t][65 + 2 * n]  = b1;
        TE[t][128 + 2 * n] = b0;
        TE[t][129 + 2 * n] = b1;
        const float fq = (float)(63 - t);
        const float eq = expf(fq * dtr);
        const float qr = eq * cosf(fq * dti), qi = eq * sinf(fq * dti);
        M1s[2 * n][t]     = __float2bfloat16(qr);
        M1s[2 * n + 1][t] = __float2bfloat16(qi);
    }
    Kt += __shfl_xor(Kt, 1);
    Kt += __shfl_xor(Kt, 2);
    if (ng == 0) Ksh[t] = Kt;
    __syncthreads();
    const float Dh = Dv[lh];
#pragma unroll
    for (int i = 0; i < 16; i++) {
        const int tau = ng * 16 + i;
        float v = (tau > t) ? 0.f : Ksh[t - tau];
        if (tau == t) v += Dh;
        TE[t][tau] = __float2bfloat16(v);
    }
    __syncthreads();
    bf16* tep = TEb + (size_t)lh * 64 * 192;
    const bf16* tes = &TE[0][0];
#pragma unroll
    for (int i = 0; i < 6; i++) {
        const int idx = i * 256 + tid;
        *(floatx4*)(tep + (size_t)idx * 8) = *(const floatx4*)(tes + (size_t)idx * 8);
    }
    bf16* m1p = M1b + (size_t)lh * 64 * 64;
    const bf16* m1s = &M1s[0][0];
#pragma unroll
    for (int i = 0; i < 2; i++) {
        const int idx = i * 256 + tid;
        *(floatx4*)(m1p + (size_t)idx * 8) = *(const floatx4*)(m1s + (size_t)idx * 8);
    }
}

// ---------------------------------------------------------------------------
// LayerNorm over H=512 on BF16 input (o1), fp32 stats, bf16 out (LN2).
// ---------------------------------------------------------------------------
__global__ void ln_bf16_kernel(const bf16* __restrict__ src,
                               const float* __restrict__ gamma, const float* __restrict__ beta,
                               bf16* __restrict__ outb) {
    const int lane = threadIdx.x & 63;
    const int row  = blockIdx.x * 4 + (threadIdx.x >> 6);
    const ushort* rp = (const ushort*)(src + (size_t)row * H);
    short8 v = *(const short8*)(rp + lane * 8);
    float f[8];
#pragma unroll
    for (int j = 0; j < 8; j++)
        f[j] = __uint_as_float(((unsigned)(ushort)v[j]) << 16);
    float s = 0.f, q = 0.f;
#pragma unroll
    for (int j = 0; j < 8; j++) { s += f[j]; q += f[j] * f[j]; }
#pragma unroll
    for (int off = 32; off > 0; off >>= 1) {
        s += __shfl_xor(s, off);
        q += __shfl_xor(q, off);
    }
    const float mean = s * (1.0f / H);
    const float var  = q * (1.0f / H) - mean * mean;
    const float rstd = rsqrtf(var + 1e-5f);
    const float4* gp = (const float4*)gamma;
    const float4* bp = (const float4*)beta;
    const float4 g0 = gp[lane * 2], g1 = gp[lane * 2 + 1];
    const float4 b0 = bp[lane * 2], b1 = bp[lane * 2 + 1];
    const float gg[8] = {g0.x, g0.y, g0.z, g0.w, g1.x, g1.y, g1.z, g1.w};
    const float bb[8] = {b0.x, b0.y, b0.z, b0.w, b1.x, b1.y, b1.z, b1.w};
    __align__(16) ushort t[8];
#pragma unroll
    for (int j = 0; j < 8; j++) {
        bf16 h = __float2bfloat16((f[j] - mean) * rstd * gg[j] + bb[j]);
        t[j] = *reinterpret_cast<ushort*>(&h);
    }
    *(floatx4*)((ushort*)outb + (size_t)row * H + lane * 8) = *(const floatx4*)t;
}

// ---------------------------------------------------------------------------
// Fused LN1 + transpose: cur[b,t,h] fp32 -> LN -> bf16 -> Ub[h][bc][tau]
// ---------------------------------------------------------------------------
__global__ __launch_bounds__(512) void ln_trans_k(const float* __restrict__ src,
                                                  const float* __restrict__ gamma,
                                                  const float* __restrict__ beta,
                                                  bf16* __restrict__ Ub) {
    __shared__ __align__(16) ushort Z[64][516];   // pad 4: row stride 1032 B, 8B-aligned
    const int bc   = blockIdx.x;
    const int tid  = threadIdx.x;
    const int lane = tid & 63;
    const int wv   = tid >> 6;                    // 0..7
    const float4* gp = (const float4*)gamma;
    const float4* bp = (const float4*)beta;
    const float4 g0 = gp[lane], g1 = gp[64 + lane];
    const float4 b0 = bp[lane], b1 = bp[64 + lane];
#pragma unroll
    for (int i = 0; i < 8; i++) {
        const int tau = wv * 8 + i;
        const float4* rp = (const float4*)(src + ((size_t)bc * 64 + tau) * H);
        const float4 v0 = rp[lane];
        const float4 v1 = rp[64 + lane];
        float s = v0.x + v0.y + v0.z + v0.w + v1.x + v1.y + v1.z + v1.w;
        float q = v0.x * v0.x + v0.y * v0.y + v0.z * v0.z + v0.w * v0.w +
                  v1.x * v1.x + v1.y * v1.y + v1.z * v1.z + v1.w * v1.w;
#pragma unroll
        for (int off = 32; off > 0; off >>= 1) {
            s += __shfl_xor(s, off);
            q += __shfl_xor(q, off);
        }
        const float mean = s * (1.0f / H);
        const float var  = q * (1.0f / H) - mean * mean;
        const float rstd = rsqrtf(var + 1e-5f);
        bf16 t0[4] = {__float2bfloat16((v0.x - mean) * rstd * g0.x + b0.x),
                      __float2bfloat16((v0.y - mean) * rstd * g0.y + b0.y),
                      __float2bfloat16((v0.z - mean) * rstd * g0.z + b0.z),
                      __float2bfloat16((v0.w - mean) * rstd * g0.w + b0.w)};
        bf16 t1[4] = {__float2bfloat16((v1.x - mean) * rstd * g1.x + b1.x),
                      __float2bfloat16((v1.y - mean) * rstd * g1.y + b1.y),
                      __float2bfloat16((v1.z - mean) * rstd * g1.z + b1.z),
                      __float2bfloat16((v1.w - mean) * rstd * g1.w + b1.w)};
        *(uint2*)&Z[tau][lane * 4]       = *(uint2*)t0;
        *(uint2*)&Z[tau][256 + lane * 4] = *(uint2*)t1;
    }
    __syncthreads();
#pragma unroll
    for (int hb = 0; hb < 8; hb++) {
        ushort* up = (ushort*)Ub + ((size_t)(hb * 64) * 512 + bc) * 64;
#pragma unroll
        for (int i = 0; i < 2; i++) {
            const int hh = i * 32 + (tid >> 4);
            const int t4 = (tid & 15) * 4;
            const int hc = hb * 64 + hh;
            ushort4 v;
            v.x = Z[t4][hc]; v.y = Z[t4 + 1][hc]; v.z = Z[t4 + 2][hc]; v.w = Z[t4 + 3][hc];
            *(ushort4*)(up + (size_t)hh * 512 * 64 + t4) = v;
        }
    }
}

// ---------------------------------------------------------------------------
// FUSED conv phase 1 + chunk scan (proven round-9).
// ---------------------------------------------------------------------------
__global__ void conv_p1s(const bf16* __restrict__ M1l, const bf16* __restrict__ Ub,
                         const float* __restrict__ dAQl, bf16* __restrict__ S0b) {
    const int h = blockIdx.x >> 2;
    const int n0 = (blockIdx.x & 3) * 128;
    __shared__ __align__(16) char sm[33024 + 34816];
    bf16(*As)[72] = (bf16(*)[72])sm;                      //  9,216 B
    bf16(*Bs)[72] = (bf16(*)[72])(sm + 9216);             // 18,432 B (ends 27,648)
    float(*Sl)[129] = (float(*)[129])sm;                  // 33,024 B (after MFMA, As/Bs dead)
    bf16(*Ob)[136] = (bf16(*)[136])(sm + 33024);          // 34,816 B
    const int tid = threadIdx.x, lane = tid & 63, wid = tid >> 6;
    const int wm = (wid & 1) * 32, wn = (wid >> 1) * 64;
#pragma unroll
    for (int i = 0; i < 2; i++) {
        int idx = i * 256 + tid, r = idx >> 3, c8 = (idx & 7) * 8;
        *(floatx4*)&As[r][c8] = *(const floatx4*)(M1l + ((size_t)h * 64 + r) * 64 + c8);
    }
#pragma unroll
    for (int i = 0; i < 4; i++) {
        int idx = i * 256 + tid, r = idx >> 3, c8 = (idx & 7) * 8;
        *(floatx4*)&Bs[r][c8] = *(const floatx4*)(Ub + ((size_t)h * 512 + n0 + r) * 64 + c8);
    }
    __syncthreads();
    floatx4 acc[2][4] = {};
#pragma unroll
    for (int ks = 0; ks < 64; ks += 32) {
        short8 af[2], bfr[4];
#pragma unroll
        for (int mt = 0; mt < 2; mt++)
            af[mt] = *(const short8*)&As[wm + mt * 16 + (lane & 15)][ks + (lane >> 4) * 8];
#pragma unroll
        for (int nt = 0; nt < 4; nt++)
            bfr[nt] = *(const short8*)&Bs[wn + nt * 16 + (lane & 15)][ks + (lane >> 4) * 8];
#pragma unroll
        for (int mt = 0; mt < 2; mt++)
#pragma unroll
            for (int nt = 0; nt < 4; nt++)
                acc[mt][nt] = __builtin_amdgcn_mfma_f32_16x16x32_bf16(af[mt], bfr[nt], acc[mt][nt], 0, 0, 0);
    }
    __syncthreads();                                 // As/Bs reads done everywhere
#pragma unroll
    for (int mt = 0; mt < 2; mt++)
#pragma unroll
        for (int nt = 0; nt < 4; nt++) {
            const int bcl = wn + nt * 16 + (lane & 15);       // local bc 0..127
#pragma unroll
            for (int r = 0; r < 4; r++) {
                const int j = wm + mt * 16 + ((lane >> 4) << 2) + r;
                Sl[j][bcl] = acc[mt][nt][r];
            }
        }
    __syncthreads();
    // scan: 64 chains = 32 complex states x 2 batches, each serial over 64 chunks
    if (tid < 64) {
        const int n = tid & 31;
        const int b = tid >> 5;                      // 0..1 (local)
        const float qr = dAQl[(h * NH + n) * 2], qi = dAQl[(h * NH + n) * 2 + 1];
        float rr = 0.f, ri = 0.f;
        for (int c = 0; c < 64; c++) {
            const int bcl = b * 64 + c;
            bf16 hr = __float2bfloat16(rr);
            bf16 hi = __float2bfloat16(ri);
            Ob[bcl][2 * n]          = hr;
            Ob[bcl][2 * n + 1]      = hi;
            Ob[bcl][64 + 2 * n]     = __float2bfloat16(rr - __bfloat162float(hr));
            Ob[bcl][64 + 2 * n + 1] = __float2bfloat16(ri - __bfloat162float(hi));
            const float lr = Sl[2 * n][bcl], li = Sl[2 * n + 1][bcl];
            const float tr = qr * rr - qi * ri + lr;
            ri = qr * ri + qi * rr + li;
            rr = tr;
        }
    }
    __syncthreads();
    bf16* op = S0b + ((size_t)h * 512 + n0) * 128;
#pragma unroll
    for (int i = 0; i < 8; i++) {
        int idx = i * 256 + tid, row = idx >> 4, c8 = (idx & 15) * 8;
        *(floatx4*)(op + (size_t)row * 128 + c8) = *(const floatx4*)&Ob[row][c8];
    }
}

// ---------------------------------------------------------------------------
// Conv phase 3 (staged, round-9 structure) with bc-tile 64 instead of 128:
// LDS 76.8 KB -> 51.2 KB => 3 blocks/CU (was 2, Occupancy 16.7%).  Grid
// doubles to H*8 = 4096 blocks.  Same MFMA fragments and k-order per output
// element -> bit-identical results.
// ---------------------------------------------------------------------------
__global__ void conv_p3(const bf16* __restrict__ TEl, const bf16* __restrict__ Ub,
                        const bf16* __restrict__ S0b, bf16* __restrict__ Yt) {
    const int h = blockIdx.x >> 3;
    const int n0 = (blockIdx.x & 7) * 64;
    __shared__ __align__(16) char sm3[(64 + 64) * 200 * 2];   // 51,200 B
    bf16(*As)[200] = (bf16(*)[200])sm3;
    bf16(*Bs)[200] = (bf16(*)[200])(sm3 + 64 * 200 * 2);
    const int tid = threadIdx.x, lane = tid & 63, wid = tid >> 6;
    const int wm = (wid & 1) * 32, wn = (wid >> 1) * 32;
#pragma unroll
    for (int i = 0; i < 6; i++) {
        int idx = i * 256 + tid, r = idx / 24, c = (idx - r * 24) * 8;
        *(floatx4*)&As[r][c] = *(const floatx4*)(TEl + ((size_t)h * 64 + r) * 192 + c);
    }
#pragma unroll
    for (int i = 0; i < 2; i++) {
        int idx = i * 256 + tid, r = idx >> 3, c8 = (idx & 7) * 8;
        *(floatx4*)&Bs[r][c8] = *(const floatx4*)(Ub + ((size_t)h * 512 + n0 + r) * 64 + c8);
    }
#pragma unroll
    for (int i = 0; i < 4; i++) {
        int idx = i * 256 + tid, r = idx >> 4, c8 = (idx & 15) * 8;
        *(floatx4*)&Bs[r][64 + c8] = *(const floatx4*)(S0b + ((size_t)h * 512 + n0 + r) * 128 + c8);
    }
    __syncthreads();
    floatx4 acc[2][2] = {};
#pragma unroll
    for (int ks = 0; ks < 192; ks += 32) {
        short8 af[2], bfr[2];
#pragma unroll
        for (int mt = 0; mt < 2; mt++)
            af[mt] = *(const short8*)&As[wm + mt * 16 + (lane & 15)][ks + (lane >> 4) * 8];
#pragma unroll
        for (int nt = 0; nt < 2; nt++)
            bfr[nt] = *(const short8*)&Bs[wn + nt * 16 + (lane & 15)][ks + (lane >> 4) * 8];
#pragma unroll
        for (int mt = 0; mt < 2; mt++)
#pragma unroll
            for (int nt = 0; nt < 2; nt++)
                acc[mt][nt] = __builtin_amdgcn_mfma_f32_16x16x32_bf16(af[mt], bfr[nt], acc[mt][nt], 0, 0, 0);
    }
    __syncthreads();
    bf16(*Tt)[72] = (bf16(*)[72])sm3;             // 64 x 72 x 2 = 9,216 B
#pragma unroll
    for (int mt = 0; mt < 2; mt++)
#pragma unroll
        for (int nt = 0; nt < 2; nt++) {
            const int n = wn + nt * 16 + (lane & 15);
#pragma unroll
            for (int r = 0; r < 4; r++) {
                const int t = wm + mt * 16 + ((lane >> 4) << 2) + r;
                Tt[n][t] = __float2bfloat16(gelu_f(acc[mt][nt][r]));
            }
        }
    __syncthreads();
#pragma unroll
    for (int i = 0; i < 2; i++) {
        int idx = i * 256 + tid, r = idx >> 3, c8 = (idx & 7) * 8;
        *(floatx4*)(Yt + ((size_t)h * 512 + n0 + r) * 64 + c8) = *(const floatx4*)&Tt[r][c8];
    }
}

// ---------------------------------------------------------------------------
// Transpose Yt[h][bc][t] -> y[b, c*64+t, h] bf16
// ---------------------------------------------------------------------------
__global__ void trans_out_k(const bf16* __restrict__ Yt, bf16* __restrict__ y) {
    const int hb = blockIdx.x & 7, bc = blockIdx.x >> 3;
    const int b = bc >> 6, c = bc & 63;
    const int h0 = hb * 64;
    __shared__ __align__(16) ushort Ti[64][68];
    const ushort* yp = (const ushort*)Yt + ((size_t)h0 * 512 + bc) * 64;
#pragma unroll
    for (int i = 0; i < 4; i++) {
        int hh = i * 16 + (threadIdx.x >> 4), t4 = (threadIdx.x & 15) * 4;
        *(ushort4*)&Ti[hh][t4] = *(const ushort4*)(yp + (size_t)hh * 512 * 64 + t4);
    }
    __syncthreads();
    ushort* op = (ushort*)y + ((size_t)b * SEQL + c * QC) * H + h0;
#pragma unroll
    for (int i = 0; i < 4; i++) {
        int tau = i * 16 + (threadIdx.x >> 4), h4 = (threadIdx.x & 15) * 4;
        ushort4 v;
        v.x = Ti[h4][tau]; v.y = Ti[h4 + 1][tau]; v.z = Ti[h4 + 2][tau]; v.w = Ti[h4 + 3][tau];
        *(ushort4*)(op + (size_t)tau * H + h4) = v;
    }
}

// ---------------------------------------------------------------------------
// bf16 MFMA GEMM with global_load_lds(16B) staging + XOR-swizzled LDS.
// PROVEN single-buffer structure (32 KB LDS) + bijective XCD swizzle.
// GEMM sync structure is frozen (r2/r7 pipeline attempts both regressed).
// ---------------------------------------------------------------------------
enum { M_BIAS = 0, M_RES = 1, M_GELU = 2, M_DUAL = 3 };

template <int MODE>
__global__ void gemm_kernel(const bf16* __restrict__ A1, const bf16* __restrict__ Wt1,
                            const bf16* __restrict__ A2, const bf16* __restrict__ Wt2,
                            const float* __restrict__ bias1, const float* __restrict__ bias2,
                            const float* __restrict__ res,
                            float* __restrict__ outf, bf16* __restrict__ outb, int KTOT) {
    __shared__ __align__(16) bf16 As[128][64];
    __shared__ __align__(16) bf16 Bs[128][64];
    const int tid  = threadIdx.x;
    const int lane = tid & 63;
    const int wid  = tid >> 6;
    const int wm   = (wid >> 1) * 64;
    const int wn   = (wid & 1) * 64;
    const int id   = blockIdx.y * 4 + blockIdx.x;
    const int q    = gridDim.y >> 1;              // nwg/8; nwg % 8 == 0 always
    const int nid  = (id & 7) * q + (id >> 3);
    const int m0   = (nid >> 2) * 128;
    const int n0   = (nid & 3) * 128;

    floatx4 acc[4][4] = {};

    for (int k0 = 0; k0 < KTOT; k0 += 64) {
        const bf16* Ap;
        const bf16* Wp;
        int kk = k0;
        if (MODE == M_DUAL && k0 >= 512) { Ap = A2; Wp = Wt2; kk = k0 - 512; }
        else                             { Ap = A1; Wp = Wt1; }
#pragma unroll
        for (int i = 0; i < 4; i++) {
            const int s   = wid * 256 + i * 64 + lane;   // 16B slot index
            const int r   = s >> 3;
            const int cbg = (s & 7) ^ (r & 7);           // swizzled source col-block
            glds16(Ap + (size_t)(m0 + r) * 512 + kk + cbg * 8,
                   (char*)&As[0][0] + (size_t)(wid * 256 + i * 64) * 16);
            glds16(Wp + (size_t)(n0 + r) * 512 + kk + cbg * 8,
                   (char*)&Bs[0][0] + (size_t)(wid * 256 + i * 64) * 16);
        }
        __syncthreads();
#pragma unroll
        for (int ks = 0; ks < 64; ks += 32) {
            short8 af[4], bfr[4];
#pragma unroll
            for (int mt = 0; mt < 4; mt++) {
                const int row = wm + mt * 16 + (lane & 15);
                const int cph = ((ks >> 3) + (lane >> 4)) ^ (row & 7);
                af[mt] = *(const short8*)&As[row][cph * 8];
            }
#pragma unroll
            for (int nt = 0; nt < 4; nt++) {
                const int row = wn + nt * 16 + (lane & 15);
                const int cph = ((ks >> 3) + (lane >> 4)) ^ (row & 7);
                bfr[nt] = *(const short8*)&Bs[row][cph * 8];
            }
#pragma unroll
            for (int mt = 0; mt < 4; mt++)
#pragma unroll
                for (int nt = 0; nt < 4; nt++)
                    acc[mt][nt] = __builtin_amdgcn_mfma_f32_16x16x32_bf16(
                        af[mt], bfr[nt], acc[mt][nt], 0, 0, 0);
        }
        __syncthreads();
    }

#pragma unroll
    for (int mt = 0; mt < 4; mt++) {
        const int rbase = m0 + wm + mt * 16 + ((lane >> 4) << 2);
#pragma unroll
        for (int nt = 0; nt < 4; nt++) {
            const int col = n0 + wn + nt * 16 + (lane & 15);
            float bsum = bias1 ? bias1[col] : 0.0f;
            if constexpr (MODE == M_DUAL) bsum += bias2[col];
#pragma unroll
            for (int r = 0; r < 4; r++) {
                const int row = rbase + r;
                float v = acc[mt][nt][r] + bsum;
                if constexpr (MODE == M_RES) v += res[(size_t)row * H + col];
                if constexpr (MODE == M_GELU) v = gelu_f(v);
                const size_t o = (size_t)row * H + col;
                if constexpr (MODE == M_DUAL) outf[o] = v;
                else                          outb[o] = __float2bfloat16(v);
            }
        }
    }
}

// ---------------------------------------------------------------------------
extern "C" void kernel_launch(void* const* d_in, const int* in_sizes, int n_in,
                              void* d_out, int out_size, void* d_ws, size_t ws_size,
                              hipStream_t stream) {
    const float* x     = (const float*)d_in[0];
    const float* ln1w  = (const float*)d_in[1];
    const float* ln1b  = (const float*)d_in[2];
    const float* ln2w  = (const float*)d_in[3];
    const float* ln2b  = (const float*)d_in[4];
    const float* logdt = (const float*)d_in[5];
    const float* Are   = (const float*)d_in[6];
    const float* Aim   = (const float*)d_in[7];
    const float* Bre   = (const float*)d_in[8];
    const float* Bim   = (const float*)d_in[9];
    const float* Cre   = (const float*)d_in[10];
    const float* Cim   = (const float*)d_in[11];
    const float* Dvec  = (const float*)d_in[12];
    const float* Wk    = (const float*)d_in[13];
    const float* bk    = (const float*)d_in[14];
    const float* W1    = (const float*)d_in[15];
    const float* b1    = (const float*)d_in[16];
    const float* W2    = (const float*)d_in[17];
    const float* b2    = (const float*)d_in[18];
    const float* Wout  = (const float*)d_in[19];
    const float* bout  = (const float*)d_in[20];
    const float* Wproj = (const float*)d_in[21];
    const float* bproj = (const float*)d_in[22];
    float* outp = (float*)d_out;

    char* p = (char*)d_ws;
    auto carve = [&](size_t bytes) -> char* {
        char* r = p;
        p += (bytes + 255) & ~(size_t)255;
        return r;
    };
    bf16*  zbA  = (bf16*)carve((size_t)MROWS * H * 2);
    bf16*  Ub   = (bf16*)carve((size_t)H * 512 * 64 * 2);
    bf16*  S0b  = (bf16*)carve((size_t)H * 512 * 128 * 2);
    bf16*  M1b  = (bf16*)carve((size_t)LYR * H * 64 * 64 * 2);
    bf16*  TEb  = (bf16*)carve((size_t)LYR * H * 64 * 192 * 2);
    float* dtAb = (float*)carve((size_t)LYR * H * NH * 2 * 4);
    float* cfb  = (float*)carve((size_t)LYR * H * NH * 2 * 4);
    float* dAQb = (float*)carve((size_t)LYR * H * NH * 2 * 4);
    bf16* wts[5];
    for (int i = 0; i < 5; i++) wts[i] = (bf16*)carve((size_t)LYR * H * H * 2);
    bf16*  Wkf = (bf16*)carve((size_t)LYR * H * H * 2);   // Wk straight bf16
    float* bcb = (float*)carve((size_t)LYR * H * 4);      // combined bias

    bf16*  Yt   = zbA;
    bf16*  bb1  = Ub;                               // Ub dead after conv_p3
    bf16*  bb0  = S0b;                              // S0b dead after conv_p3
    bf16*  bb2  = S0b + (size_t)MROWS * H;          // second half of S0b

    const float* wsrc[5] = {Wk, W1, W2, Wout, Wproj};
    {
        dim3 g(8, 8, LYR);
        for (int i = 0; i < 5; i++)
            cast_w_kernel<<<g, 256, 0, stream>>>(wsrc[i], wts[i], i == 0 ? Wkf : nullptr);
    }
    // Collapse Wk@W1 -> Wct (into wts[0]): Wct[n][m] = sum_k W1t[n][k]*Wkf[m][k]
    wc_gemm<<<dim3(8, 8, LYR), 256, 0, stream>>>(wts[1], Wkf, wts[0]);
    bias_comb_kernel<<<dim3(8, LYR), 256, 0, stream>>>(bk, W1, b1, bcb);

    ssm_params_kernel<<<(LYR * H * NH) / 256, 256, 0, stream>>>(
        logdt, Are, Aim, Bre, Bim, Cre, Cim, dtAb, cfb, dAQb);
    prep_mats<<<LYR * H, 256, 0, stream>>>(dtAb, cfb, Dvec, M1b, TEb);

    const float* cur = x;
    for (int l = 0; l < LYR; l++) {
        ln_trans_k<<<MROWS / 64, 512, 0, stream>>>(cur, ln1w + l * H, ln1b + l * H, Ub);
        conv_p1s<<<H * 4, 256, 0, stream>>>(M1b + (size_t)l * H * 64 * 64, Ub,
                                            dAQb + (size_t)l * H * NH * 2, S0b);
        conv_p3<<<H * 8, 256, 0, stream>>>(TEb + (size_t)l * H * 64 * 192, Ub, S0b, Yt);
        trans_out_k<<<BATCH * NC * 8, 256, 0, stream>>>(Yt, bb0);   // bb0 = y_gelu bf16

        dim3 gg(H / 128, MROWS / 128);
        // o1 = y_gelu @ Wc + bc + out   -> bf16 ONLY (no fp32 round-trip)
        gemm_kernel<M_RES><<<gg, 256, 0, stream>>>(
            bb0, wts[0] + (size_t)l * H * H, nullptr, nullptr,
            bcb + l * H, nullptr, cur, nullptr, bb1, 512);
        // LN2 on bf16 o1 (fp32 stats)
        ln_bf16_kernel<<<MROWS / 4, 256, 0, stream>>>(bb1, ln2w + l * H, ln2b + l * H, bb0);
        gemm_kernel<M_GELU><<<gg, 256, 0, stream>>>(
            bb0, wts[2] + (size_t)l * H * H, nullptr, nullptr,
            b2 + l * H, nullptr, nullptr, nullptr, bb2, 512);
        gemm_kernel<M_DUAL><<<gg, 256, 0, stream>>>(
            bb2, wts[3] + (size_t)l * H * H, bb1, wts[4] + (size_t)l * H * H,
            bout + l * H, bproj + l * H, nullptr, outp, nullptr, 1024);
        cur = outp;
    }
}

// Round 12
// 635.094 us; speedup vs baseline: 1.2048x; 1.0551x over previous
//
#include <hip/hip_runtime.h>
#include <hip/hip_bf16.h>
#include <math.h>

#define LYR   2
#define H     512
#define NH    32
#define BATCH 8
#define SEQL  4096
#define QC    64
#define NC    (SEQL / QC)
#define MROWS (BATCH * SEQL)

typedef __attribute__((ext_vector_type(8))) short short8;
typedef __attribute__((ext_vector_type(4))) float floatx4;
typedef __hip_bfloat16 bf16;

__device__ __forceinline__ float gelu_f(float x) {
    return 0.5f * x * (1.0f + erff(x * 0.70710678118654752440f));
}

__device__ __forceinline__ void glds16(const void* g, void* l) {
    __builtin_amdgcn_global_load_lds((const __attribute__((address_space(1))) void*)g,
                                     (__attribute__((address_space(3))) void*)l, 16, 0, 0);
}

__device__ __forceinline__ ushort bf16_bits(float x) {
    bf16 h = __float2bfloat16(x);
    return *reinterpret_cast<ushort*>(&h);
}

// ---------------------------------------------------------------------------
// Weight cast + transpose: W[l][k][n] fp32 -> Wt[l][n][k] bf16
// Optionally also emits the straight (non-transposed) bf16 copy into Wf.
// ---------------------------------------------------------------------------
__global__ void cast_w_kernel(const float* __restrict__ W, bf16* __restrict__ Wt,
                              bf16* __restrict__ Wf) {
    __shared__ __align__(16) float tile[64][65];
    const int l  = blockIdx.z;
    const int k0 = blockIdx.y * 64;
    const int n0 = blockIdx.x * 64;
    const float* src = W + (size_t)l * H * H;
    bf16* dst = Wt + (size_t)l * H * H;
    bf16* dstf = Wf ? (Wf + (size_t)l * H * H) : nullptr;
#pragma unroll
    for (int i = 0; i < 16; i++) {
        int e = i * 256 + threadIdx.x;
        int r = e >> 6, c = e & 63;
        const float v = src[(size_t)(k0 + r) * H + n0 + c];
        tile[r][c] = v;
        if (dstf) dstf[(size_t)(k0 + r) * H + n0 + c] = __float2bfloat16(v);
    }
    __syncthreads();
#pragma unroll
    for (int i = 0; i < 16; i++) {
        int e = i * 256 + threadIdx.x;
        int r = e >> 6, c = e & 63;
        dst[(size_t)(n0 + r) * H + k0 + c] = __float2bfloat16(tile[c][r]);
    }
}

// ---------------------------------------------------------------------------
// Wct[l][n][m] = sum_k W1t[l][n][k] * Wkf[l][m][k]  ( = (Wk@W1)^T, bf16 )
// ---------------------------------------------------------------------------
__global__ void wc_gemm(const bf16* __restrict__ W1t, const bf16* __restrict__ Wkf,
                        bf16* __restrict__ Wct) {
    const int l  = blockIdx.z;
    const int n0 = blockIdx.y * 64;
    const int m0 = blockIdx.x * 64;
    const bf16* A = W1t + (size_t)l * H * H;   // [n][k]
    const bf16* B = Wkf + (size_t)l * H * H;   // [m][k]
    bf16* O = Wct + (size_t)l * H * H;         // [n][m]
    __shared__ __align__(16) bf16 As[64][72];
    __shared__ __align__(16) bf16 Bs[64][72];
    const int tid = threadIdx.x, lane = tid & 63, wid = tid >> 6;
    const int wn = (wid >> 1) * 32, wm = (wid & 1) * 32;
    floatx4 acc[2][2] = {};
    for (int kk = 0; kk < 512; kk += 64) {
#pragma unroll
        for (int i = 0; i < 2; i++) {
            int idx = i * 256 + tid, r = idx >> 3, c8 = (idx & 7) * 8;
            *(floatx4*)&As[r][c8] = *(const floatx4*)(A + (size_t)(n0 + r) * 512 + kk + c8);
            *(floatx4*)&Bs[r][c8] = *(const floatx4*)(B + (size_t)(m0 + r) * 512 + kk + c8);
        }
        __syncthreads();
#pragma unroll
        for (int ks = 0; ks < 64; ks += 32) {
            short8 af[2], bfr[2];
#pragma unroll
            for (int mt = 0; mt < 2; mt++)
                af[mt] = *(const short8*)&As[wn + mt * 16 + (lane & 15)][ks + (lane >> 4) * 8];
#pragma unroll
            for (int nt = 0; nt < 2; nt++)
                bfr[nt] = *(const short8*)&Bs[wm + nt * 16 + (lane & 15)][ks + (lane >> 4) * 8];
#pragma unroll
            for (int mt = 0; mt < 2; mt++)
#pragma unroll
                for (int nt = 0; nt < 2; nt++)
                    acc[mt][nt] = __builtin_amdgcn_mfma_f32_16x16x32_bf16(
                        af[mt], bfr[nt], acc[mt][nt], 0, 0, 0);
        }
        __syncthreads();
    }
#pragma unroll
    for (int mt = 0; mt < 2; mt++)
#pragma unroll
        for (int nt = 0; nt < 2; nt++) {
            const int col = m0 + wm + nt * 16 + (lane & 15);
#pragma unroll
            for (int r = 0; r < 4; r++) {
                const int row = n0 + wn + mt * 16 + ((lane >> 4) << 2) + r;
                O[(size_t)row * 512 + col] = __float2bfloat16(acc[mt][nt][r]);
            }
        }
}

// ---------------------------------------------------------------------------
// bc[l][n] = b1[l][n] + sum_k bk[l][k] * W1[l][k][n]
// ---------------------------------------------------------------------------
__global__ void bias_comb_kernel(const float* __restrict__ bk, const float* __restrict__ W1,
                                 const float* __restrict__ b1, float* __restrict__ bc) {
    const int l  = blockIdx.y;
    const int n  = blockIdx.x * 64 + (threadIdx.x & 63);
    const int kq = threadIdx.x >> 6;
    float s = 0.f;
    for (int k = kq * 128; k < kq * 128 + 128; k++)
        s += bk[l * H + k] * W1[((size_t)l * H + k) * H + n];
    __shared__ float red[4][64];
    red[kq][threadIdx.x & 63] = s;
    __syncthreads();
    if (threadIdx.x < 64) {
        bc[l * H + n] = red[0][threadIdx.x] + red[1][threadIdx.x] +
                        red[2][threadIdx.x] + red[3][threadIdx.x] + b1[l * H + n];
    }
}

// ---------------------------------------------------------------------------
// SSM discretization: dtA = dt*A, coef = C*B*(exp(dtA)-1)/A, dAQ = exp(dtA)^QC
// ---------------------------------------------------------------------------
__global__ void ssm_params_kernel(const float* __restrict__ log_dt,
                                  const float* __restrict__ A_re, const float* __restrict__ A_im,
                                  const float* __restrict__ B_re, const float* __restrict__ B_im,
                                  const float* __restrict__ C_re, const float* __restrict__ C_im,
                                  float* __restrict__ dtA, float* __restrict__ coef,
                                  float* __restrict__ dAQ) {
    const int idx = blockIdx.x * 256 + threadIdx.x;
    if (idx >= LYR * H * NH) return;
    const int lh = idx >> 5;
    const float dt  = expf(log_dt[lh]);
    const float are = A_re[idx], aim = A_im[idx];
    const float e   = expf(dt * are);
    const float dre = e * cosf(dt * aim);
    const float dim_ = e * sinf(dt * aim);
    const float den = are * are + aim * aim;
    const float nre = dre - 1.0f, nim = dim_;
    const float qre = (nre * are + nim * aim) / den;
    const float qim = (nim * are - nre * aim) / den;
    const float bre = B_re[idx], bim = B_im[idx];
    const float dbre = bre * qre - bim * qim;
    const float dbim = bre * qim + bim * qre;
    const float cre = C_re[idx], cim = C_im[idx];
    coef[2 * idx]     = cre * dbre - cim * dbim;
    coef[2 * idx + 1] = cre * dbim + cim * dbre;
    dtA[2 * idx]     = dt * are;
    dtA[2 * idx + 1] = dt * aim;
    const float eq = expf((float)QC * dt * are);
    const float ph = (float)QC * dt * aim;
    dAQ[2 * idx]     = eq * cosf(ph);
    dAQ[2 * idx + 1] = eq * sinf(ph);
}

// ---------------------------------------------------------------------------
// Build per-(l,h) conv matrices — closed-form powers, fully parallel.
// ---------------------------------------------------------------------------
__global__ void prep_mats(const float* __restrict__ dtA, const float* __restrict__ coef,
                          const float* __restrict__ Dv,
                          bf16* __restrict__ M1b, bf16* __restrict__ TEb) {
    const int lh  = blockIdx.x;
    const int tid = threadIdx.x;
    const int t   = tid >> 2;
    const int ng  = tid & 3;
    __shared__ float Ksh[64];
    __shared__ __align__(16) bf16 TE[64][192];
    __shared__ __align__(16) bf16 M1s[64][64];

    const float ft = (float)t;
    float Kt = 0.f;
#pragma unroll
    for (int k = 0; k < 8; k++) {
        const int n = ng * 8 + k;
        const float dtr = dtA[((size_t)lh * NH + n) * 2];
        const float dti = dtA[((size_t)lh * NH + n) * 2 + 1];
        const float cre = coef[((size_t)lh * NH + n) * 2];
        const float cim = coef[((size_t)lh * NH + n) * 2 + 1];
        const float er  = expf(dtr);
        const float dre = er * cosf(dti), dim_ = er * sinf(dti);
        const float et = expf(ft * dtr);
        const float pr = et * cosf(ft * dti), pi = et * sinf(ft * dti);
        Kt = fmaf(2.f * cre, pr, fmaf(-2.f * cim, pi, Kt));
        const float per = pr * dre - pi * dim_;
        const float pei = pr * dim_ + pi * dre;
        const float e0 = 2.f * (cre * per - cim * pei);
        const float e1 = -2.f * (cre * pei + cim * per);
        const bf16 b0 = __float2bfloat16(e0), b1 = __float2bfloat16(e1);
        TE[t][64 + 2 * n]  = b0;
        TE[t][65 + 2 * n]  = b1;
        TE[t][128 + 2 * n] = b0;
        TE[t][129 + 2 * n] = b1;
        const float fq = (float)(63 - t);
        const float eq = expf(fq * dtr);
        const float qr = eq * cosf(fq * dti), qi = eq * sinf(fq * dti);
        M1s[2 * n][t]     = __float2bfloat16(qr);
        M1s[2 * n + 1][t] = __float2bfloat16(qi);
    }
    Kt += __shfl_xor(Kt, 1);
    Kt += __shfl_xor(Kt, 2);
    if (ng == 0) Ksh[t] = Kt;
    __syncthreads();
    const float Dh = Dv[lh];
#pragma unroll
    for (int i = 0; i < 16; i++) {
        const int tau = ng * 16 + i;
        float v = (tau > t) ? 0.f : Ksh[t - tau];
        if (tau == t) v += Dh;
        TE[t][tau] = __float2bfloat16(v);
    }
    __syncthreads();
    bf16* tep = TEb + (size_t)lh * 64 * 192;
    const bf16* tes = &TE[0][0];
#pragma unroll
    for (int i = 0; i < 6; i++) {
        const int idx = i * 256 + tid;
        *(floatx4*)(tep + (size_t)idx * 8) = *(const floatx4*)(tes + (size_t)idx * 8);
    }
    bf16* m1p = M1b + (size_t)lh * 64 * 64;
    const bf16* m1s = &M1s[0][0];
#pragma unroll
    for (int i = 0; i < 2; i++) {
        const int idx = i * 256 + tid;
        *(floatx4*)(m1p + (size_t)idx * 8) = *(const floatx4*)(m1s + (size_t)idx * 8);
    }
}

// ---------------------------------------------------------------------------
// LayerNorm over H=512 on BF16 input (o1), fp32 stats, bf16 out (LN2).
// ---------------------------------------------------------------------------
__global__ void ln_bf16_kernel(const bf16* __restrict__ src,
                               const float* __restrict__ gamma, const float* __restrict__ beta,
                               bf16* __restrict__ outb) {
    const int lane = threadIdx.x & 63;
    const int row  = blockIdx.x * 4 + (threadIdx.x >> 6);
    const ushort* rp = (const ushort*)(src + (size_t)row * H);
    short8 v = *(const short8*)(rp + lane * 8);
    float f[8];
#pragma unroll
    for (int j = 0; j < 8; j++)
        f[j] = __uint_as_float(((unsigned)(ushort)v[j]) << 16);
    float s = 0.f, q = 0.f;
#pragma unroll
    for (int j = 0; j < 8; j++) { s += f[j]; q += f[j] * f[j]; }
#pragma unroll
    for (int off = 32; off > 0; off >>= 1) {
        s += __shfl_xor(s, off);
        q += __shfl_xor(q, off);
    }
    const float mean = s * (1.0f / H);
    const float var  = q * (1.0f / H) - mean * mean;
    const float rstd = rsqrtf(var + 1e-5f);
    const float4* gp = (const float4*)gamma;
    const float4* bp = (const float4*)beta;
    const float4 g0 = gp[lane * 2], g1 = gp[lane * 2 + 1];
    const float4 b0 = bp[lane * 2], b1 = bp[lane * 2 + 1];
    const float gg[8] = {g0.x, g0.y, g0.z, g0.w, g1.x, g1.y, g1.z, g1.w};
    const float bb[8] = {b0.x, b0.y, b0.z, b0.w, b1.x, b1.y, b1.z, b1.w};
    __align__(16) ushort t[8];
#pragma unroll
    for (int j = 0; j < 8; j++) {
        bf16 h = __float2bfloat16((f[j] - mean) * rstd * gg[j] + bb[j]);
        t[j] = *reinterpret_cast<ushort*>(&h);
    }
    *(floatx4*)((ushort*)outb + (size_t)row * H + lane * 8) = *(const floatx4*)t;
}

// ---------------------------------------------------------------------------
// Fused LN1 + transpose: cur[b,t,h] fp32 -> LN -> bf16 -> Ub[h][bc][tau]
// ---------------------------------------------------------------------------
__global__ __launch_bounds__(512) void ln_trans_k(const float* __restrict__ src,
                                                  const float* __restrict__ gamma,
                                                  const float* __restrict__ beta,
                                                  bf16* __restrict__ Ub) {
    __shared__ __align__(16) ushort Z[64][516];   // pad 4: row stride 1032 B, 8B-aligned
    const int bc   = blockIdx.x;
    const int tid  = threadIdx.x;
    const int lane = tid & 63;
    const int wv   = tid >> 6;                    // 0..7
    const float4* gp = (const float4*)gamma;
    const float4* bp = (const float4*)beta;
    const float4 g0 = gp[lane], g1 = gp[64 + lane];
    const float4 b0 = bp[lane], b1 = bp[64 + lane];
#pragma unroll
    for (int i = 0; i < 8; i++) {
        const int tau = wv * 8 + i;
        const float4* rp = (const float4*)(src + ((size_t)bc * 64 + tau) * H);
        const float4 v0 = rp[lane];
        const float4 v1 = rp[64 + lane];
        float s = v0.x + v0.y + v0.z + v0.w + v1.x + v1.y + v1.z + v1.w;
        float q = v0.x * v0.x + v0.y * v0.y + v0.z * v0.z + v0.w * v0.w +
                  v1.x * v1.x + v1.y * v1.y + v1.z * v1.z + v1.w * v1.w;
#pragma unroll
        for (int off = 32; off > 0; off >>= 1) {
            s += __shfl_xor(s, off);
            q += __shfl_xor(q, off);
        }
        const float mean = s * (1.0f / H);
        const float var  = q * (1.0f / H) - mean * mean;
        const float rstd = rsqrtf(var + 1e-5f);
        bf16 t0[4] = {__float2bfloat16((v0.x - mean) * rstd * g0.x + b0.x),
                      __float2bfloat16((v0.y - mean) * rstd * g0.y + b0.y),
                      __float2bfloat16((v0.z - mean) * rstd * g0.z + b0.z),
                      __float2bfloat16((v0.w - mean) * rstd * g0.w + b0.w)};
        bf16 t1[4] = {__float2bfloat16((v1.x - mean) * rstd * g1.x + b1.x),
                      __float2bfloat16((v1.y - mean) * rstd * g1.y + b1.y),
                      __float2bfloat16((v1.z - mean) * rstd * g1.z + b1.z),
                      __float2bfloat16((v1.w - mean) * rstd * g1.w + b1.w)};
        *(uint2*)&Z[tau][lane * 4]       = *(uint2*)t0;
        *(uint2*)&Z[tau][256 + lane * 4] = *(uint2*)t1;
    }
    __syncthreads();
#pragma unroll
    for (int hb = 0; hb < 8; hb++) {
        ushort* up = (ushort*)Ub + ((size_t)(hb * 64) * 512 + bc) * 64;
#pragma unroll
        for (int i = 0; i < 2; i++) {
            const int hh = i * 32 + (tid >> 4);
            const int t4 = (tid & 15) * 4;
            const int hc = hb * 64 + hh;
            ushort4 v;
            v.x = Z[t4][hc]; v.y = Z[t4 + 1][hc]; v.z = Z[t4 + 2][hc]; v.w = Z[t4 + 3][hc];
            *(ushort4*)(up + (size_t)hh * 512 * 64 + t4) = v;
        }
    }
}

// ---------------------------------------------------------------------------
// FUSED conv phase 1 + chunk scan — scan stores DIRECTLY to S0b.
// At each chunk step c, lanes n=0..31 of each half-wave write two contiguous
// 128 B segments of one 256 B S0b row (hi at +0, lo at +128 B) — already
// coalesced, so the Ob staging buffer (34.8 KB) is deleted.  LDS drops
// 67.8 KB -> 33 KB => 4 blocks/CU (was 2).  Waves 1-3 retire after the Sl
// barrier.  S0b bytes identical to round-11 (same values, same rounding).
// ---------------------------------------------------------------------------
__global__ void conv_p1s(const bf16* __restrict__ M1l, const bf16* __restrict__ Ub,
                         const float* __restrict__ dAQl, bf16* __restrict__ S0b) {
    const int h = blockIdx.x >> 2;
    const int n0 = (blockIdx.x & 3) * 128;
    __shared__ __align__(16) char sm[33024];
    bf16(*As)[72] = (bf16(*)[72])sm;                      //  9,216 B
    bf16(*Bs)[72] = (bf16(*)[72])(sm + 9216);             // 18,432 B (ends 27,648)
    float(*Sl)[129] = (float(*)[129])sm;                  // 33,024 B (after MFMA, As/Bs dead)
    const int tid = threadIdx.x, lane = tid & 63, wid = tid >> 6;
    const int wm = (wid & 1) * 32, wn = (wid >> 1) * 64;
#pragma unroll
    for (int i = 0; i < 2; i++) {
        int idx = i * 256 + tid, r = idx >> 3, c8 = (idx & 7) * 8;
        *(floatx4*)&As[r][c8] = *(const floatx4*)(M1l + ((size_t)h * 64 + r) * 64 + c8);
    }
#pragma unroll
    for (int i = 0; i < 4; i++) {
        int idx = i * 256 + tid, r = idx >> 3, c8 = (idx & 7) * 8;
        *(floatx4*)&Bs[r][c8] = *(const floatx4*)(Ub + ((size_t)h * 512 + n0 + r) * 64 + c8);
    }
    __syncthreads();
    floatx4 acc[2][4] = {};
#pragma unroll
    for (int ks = 0; ks < 64; ks += 32) {
        short8 af[2], bfr[4];
#pragma unroll
        for (int mt = 0; mt < 2; mt++)
            af[mt] = *(const short8*)&As[wm + mt * 16 + (lane & 15)][ks + (lane >> 4) * 8];
#pragma unroll
        for (int nt = 0; nt < 4; nt++)
            bfr[nt] = *(const short8*)&Bs[wn + nt * 16 + (lane & 15)][ks + (lane >> 4) * 8];
#pragma unroll
        for (int mt = 0; mt < 2; mt++)
#pragma unroll
            for (int nt = 0; nt < 4; nt++)
                acc[mt][nt] = __builtin_amdgcn_mfma_f32_16x16x32_bf16(af[mt], bfr[nt], acc[mt][nt], 0, 0, 0);
    }
    __syncthreads();                                 // As/Bs reads done everywhere
#pragma unroll
    for (int mt = 0; mt < 2; mt++)
#pragma unroll
        for (int nt = 0; nt < 4; nt++) {
            const int bcl = wn + nt * 16 + (lane & 15);       // local bc 0..127
#pragma unroll
            for (int r = 0; r < 4; r++) {
                const int j = wm + mt * 16 + ((lane >> 4) << 2) + r;
                Sl[j][bcl] = acc[mt][nt][r];
            }
        }
    __syncthreads();
    // scan: 64 chains = 32 complex states x 2 batches, serial over 64 chunks;
    // direct coalesced stores (hi pair at +4n B, lo pair at +128+4n B per row)
    if (tid < 64) {
        const int n = tid & 31;
        const int b = tid >> 5;                      // 0..1 (local)
        const float qr = dAQl[(h * NH + n) * 2], qi = dAQl[(h * NH + n) * 2 + 1];
        float rr = 0.f, ri = 0.f;
        for (int c = 0; c < 64; c++) {
            const ushort u0 = bf16_bits(rr);
            const ushort u1 = bf16_bits(ri);
            const float hr = __uint_as_float(((unsigned)u0) << 16);
            const float hi = __uint_as_float(((unsigned)u1) << 16);
            const ushort l0 = bf16_bits(rr - hr);
            const ushort l1 = bf16_bits(ri - hi);
            bf16* rowp = S0b + ((size_t)h * 512 + n0 + b * 64 + c) * 128;
            *(unsigned*)&rowp[2 * n]      = (unsigned)u0 | ((unsigned)u1 << 16);
            *(unsigned*)&rowp[64 + 2 * n] = (unsigned)l0 | ((unsigned)l1 << 16);
            const int bcl = b * 64 + c;
            const float lr = Sl[2 * n][bcl], li = Sl[2 * n + 1][bcl];
            const float tr = qr * rr - qi * ri + lr;
            ri = qr * ri + qi * rr + li;
            rr = tr;
        }
    }
}

// ---------------------------------------------------------------------------
// Conv phase 3 (staged, bc-tile 64): LDS 51.2 KB -> 3 blocks/CU.
// ---------------------------------------------------------------------------
__global__ void conv_p3(const bf16* __restrict__ TEl, const bf16* __restrict__ Ub,
                        const bf16* __restrict__ S0b, bf16* __restrict__ Yt) {
    const int h = blockIdx.x >> 3;
    const int n0 = (blockIdx.x & 7) * 64;
    __shared__ __align__(16) char sm3[(64 + 64) * 200 * 2];   // 51,200 B
    bf16(*As)[200] = (bf16(*)[200])sm3;
    bf16(*Bs)[200] = (bf16(*)[200])(sm3 + 64 * 200 * 2);
    const int tid = threadIdx.x, lane = tid & 63, wid = tid >> 6;
    const int wm = (wid & 1) * 32, wn = (wid >> 1) * 32;
#pragma unroll
    for (int i = 0; i < 6; i++) {
        int idx = i * 256 + tid, r = idx / 24, c = (idx - r * 24) * 8;
        *(floatx4*)&As[r][c] = *(const floatx4*)(TEl + ((size_t)h * 64 + r) * 192 + c);
    }
#pragma unroll
    for (int i = 0; i < 2; i++) {
        int idx = i * 256 + tid, r = idx >> 3, c8 = (idx & 7) * 8;
        *(floatx4*)&Bs[r][c8] = *(const floatx4*)(Ub + ((size_t)h * 512 + n0 + r) * 64 + c8);
    }
#pragma unroll
    for (int i = 0; i < 4; i++) {
        int idx = i * 256 + tid, r = idx >> 4, c8 = (idx & 15) * 8;
        *(floatx4*)&Bs[r][64 + c8] = *(const floatx4*)(S0b + ((size_t)h * 512 + n0 + r) * 128 + c8);
    }
    __syncthreads();
    floatx4 acc[2][2] = {};
#pragma unroll
    for (int ks = 0; ks < 192; ks += 32) {
        short8 af[2], bfr[2];
#pragma unroll
        for (int mt = 0; mt < 2; mt++)
            af[mt] = *(const short8*)&As[wm + mt * 16 + (lane & 15)][ks + (lane >> 4) * 8];
#pragma unroll
        for (int nt = 0; nt < 2; nt++)
            bfr[nt] = *(const short8*)&Bs[wn + nt * 16 + (lane & 15)][ks + (lane >> 4) * 8];
#pragma unroll
        for (int mt = 0; mt < 2; mt++)
#pragma unroll
            for (int nt = 0; nt < 2; nt++)
                acc[mt][nt] = __builtin_amdgcn_mfma_f32_16x16x32_bf16(af[mt], bfr[nt], acc[mt][nt], 0, 0, 0);
    }
    __syncthreads();
    bf16(*Tt)[72] = (bf16(*)[72])sm3;             // 64 x 72 x 2 = 9,216 B
#pragma unroll
    for (int mt = 0; mt < 2; mt++)
#pragma unroll
        for (int nt = 0; nt < 2; nt++) {
            const int n = wn + nt * 16 + (lane & 15);
#pragma unroll
            for (int r = 0; r < 4; r++) {
                const int t = wm + mt * 16 + ((lane >> 4) << 2) + r;
                Tt[n][t] = __float2bfloat16(gelu_f(acc[mt][nt][r]));
            }
        }
    __syncthreads();
#pragma unroll
    for (int i = 0; i < 2; i++) {
        int idx = i * 256 + tid, r = idx >> 3, c8 = (idx & 7) * 8;
        *(floatx4*)(Yt + ((size_t)h * 512 + n0 + r) * 64 + c8) = *(const floatx4*)&Tt[r][c8];
    }
}

// ---------------------------------------------------------------------------
// Transpose Yt[h][bc][t] -> y[b, c*64+t, h] bf16
// ---------------------------------------------------------------------------
__global__ void trans_out_k(const bf16* __restrict__ Yt, bf16* __restrict__ y) {
    const int hb = blockIdx.x & 7, bc = blockIdx.x >> 3;
    const int b = bc >> 6, c = bc & 63;
    const int h0 = hb * 64;
    __shared__ __align__(16) ushort Ti[64][68];
    const ushort* yp = (const ushort*)Yt + ((size_t)h0 * 512 + bc) * 64;
#pragma unroll
    for (int i = 0; i < 4; i++) {
        int hh = i * 16 + (threadIdx.x >> 4), t4 = (threadIdx.x & 15) * 4;
        *(ushort4*)&Ti[hh][t4] = *(const ushort4*)(yp + (size_t)hh * 512 * 64 + t4);
    }
    __syncthreads();
    ushort* op = (ushort*)y + ((size_t)b * SEQL + c * QC) * H + h0;
#pragma unroll
    for (int i = 0; i < 4; i++) {
        int tau = i * 16 + (threadIdx.x >> 4), h4 = (threadIdx.x & 15) * 4;
        ushort4 v;
        v.x = Ti[h4][tau]; v.y = Ti[h4 + 1][tau]; v.z = Ti[h4 + 2][tau]; v.w = Ti[h4 + 3][tau];
        *(ushort4*)(op + (size_t)tau * H + h4) = v;
    }
}

// ---------------------------------------------------------------------------
// bf16 MFMA GEMM with global_load_lds(16B) staging + XOR-swizzled LDS.
// PROVEN single-buffer structure (32 KB LDS) + bijective XCD swizzle.
// GEMM sync structure is frozen (r2/r7 pipeline attempts both regressed).
// ---------------------------------------------------------------------------
enum { M_BIAS = 0, M_RES = 1, M_GELU = 2, M_DUAL = 3 };

template <int MODE>
__global__ void gemm_kernel(const bf16* __restrict__ A1, const bf16* __restrict__ Wt1,
                            const bf16* __restrict__ A2, const bf16* __restrict__ Wt2,
                            const float* __restrict__ bias1, const float* __restrict__ bias2,
                            const float* __restrict__ res,
                            float* __restrict__ outf, bf16* __restrict__ outb, int KTOT) {
    __shared__ __align__(16) bf16 As[128][64];
    __shared__ __align__(16) bf16 Bs[128][64];
    const int tid  = threadIdx.x;
    const int lane = tid & 63;
    const int wid  = tid >> 6;
    const int wm   = (wid >> 1) * 64;
    const int wn   = (wid & 1) * 64;
    const int id   = blockIdx.y * 4 + blockIdx.x;
    const int q    = gridDim.y >> 1;              // nwg/8; nwg % 8 == 0 always
    const int nid  = (id & 7) * q + (id >> 3);
    const int m0   = (nid >> 2) * 128;
    const int n0   = (nid & 3) * 128;

    floatx4 acc[4][4] = {};

    for (int k0 = 0; k0 < KTOT; k0 += 64) {
        const bf16* Ap;
        const bf16* Wp;
        int kk = k0;
        if (MODE == M_DUAL && k0 >= 512) { Ap = A2; Wp = Wt2; kk = k0 - 512; }
        else                             { Ap = A1; Wp = Wt1; }
#pragma unroll
        for (int i = 0; i < 4; i++) {
            const int s   = wid * 256 + i * 64 + lane;   // 16B slot index
            const int r   = s >> 3;
            const int cbg = (s & 7) ^ (r & 7);           // swizzled source col-block
            glds16(Ap + (size_t)(m0 + r) * 512 + kk + cbg * 8,
                   (char*)&As[0][0] + (size_t)(wid * 256 + i * 64) * 16);
            glds16(Wp + (size_t)(n0 + r) * 512 + kk + cbg * 8,
                   (char*)&Bs[0][0] + (size_t)(wid * 256 + i * 64) * 16);
        }
        __syncthreads();
#pragma unroll
        for (int ks = 0; ks < 64; ks += 32) {
            short8 af[4], bfr[4];
#pragma unroll
            for (int mt = 0; mt < 4; mt++) {
                const int row = wm + mt * 16 + (lane & 15);
                const int cph = ((ks >> 3) + (lane >> 4)) ^ (row & 7);
                af[mt] = *(const short8*)&As[row][cph * 8];
            }
#pragma unroll
            for (int nt = 0; nt < 4; nt++) {
                const int row = wn + nt * 16 + (lane & 15);
                const int cph = ((ks >> 3) + (lane >> 4)) ^ (row & 7);
                bfr[nt] = *(const short8*)&Bs[row][cph * 8];
            }
#pragma unroll
            for (int mt = 0; mt < 4; mt++)
#pragma unroll
                for (int nt = 0; nt < 4; nt++)
                    acc[mt][nt] = __builtin_amdgcn_mfma_f32_16x16x32_bf16(
                        af[mt], bfr[nt], acc[mt][nt], 0, 0, 0);
        }
        __syncthreads();
    }

#pragma unroll
    for (int mt = 0; mt < 4; mt++) {
        const int rbase = m0 + wm + mt * 16 + ((lane >> 4) << 2);
#pragma unroll
        for (int nt = 0; nt < 4; nt++) {
            const int col = n0 + wn + nt * 16 + (lane & 15);
            float bsum = bias1 ? bias1[col] : 0.0f;
            if constexpr (MODE == M_DUAL) bsum += bias2[col];
#pragma unroll
            for (int r = 0; r < 4; r++) {
                const int row = rbase + r;
                float v = acc[mt][nt][r] + bsum;
                if constexpr (MODE == M_RES) v += res[(size_t)row * H + col];
                if constexpr (MODE == M_GELU) v = gelu_f(v);
                const size_t o = (size_t)row * H + col;
                if constexpr (MODE == M_DUAL) outf[o] = v;
                else                          outb[o] = __float2bfloat16(v);
            }
        }
    }
}

// ---------------------------------------------------------------------------
extern "C" void kernel_launch(void* const* d_in, const int* in_sizes, int n_in,
                              void* d_out, int out_size, void* d_ws, size_t ws_size,
                              hipStream_t stream) {
    const float* x     = (const float*)d_in[0];
    const float* ln1w  = (const float*)d_in[1];
    const float* ln1b  = (const float*)d_in[2];
    const float* ln2w  = (const float*)d_in[3];
    const float* ln2b  = (const float*)d_in[4];
    const float* logdt = (const float*)d_in[5];
    const float* Are   = (const float*)d_in[6];
    const float* Aim   = (const float*)d_in[7];
    const float* Bre   = (const float*)d_in[8];
    const float* Bim   = (const float*)d_in[9];
    const float* Cre   = (const float*)d_in[10];
    const float* Cim   = (const float*)d_in[11];
    const float* Dvec  = (const float*)d_in[12];
    const float* Wk    = (const float*)d_in[13];
    const float* bk    = (const float*)d_in[14];
    const float* W1    = (const float*)d_in[15];
    const float* b1    = (const float*)d_in[16];
    const float* W2    = (const float*)d_in[17];
    const float* b2    = (const float*)d_in[18];
    const float* Wout  = (const float*)d_in[19];
    const float* bout  = (const float*)d_in[20];
    const float* Wproj = (const float*)d_in[21];
    const float* bproj = (const float*)d_in[22];
    float* outp = (float*)d_out;

    char* p = (char*)d_ws;
    auto carve = [&](size_t bytes) -> char* {
        char* r = p;
        p += (bytes + 255) & ~(size_t)255;
        return r;
    };
    bf16*  zbA  = (bf16*)carve((size_t)MROWS * H * 2);
    bf16*  Ub   = (bf16*)carve((size_t)H * 512 * 64 * 2);
    bf16*  S0b  = (bf16*)carve((size_t)H * 512 * 128 * 2);
    bf16*  M1b  = (bf16*)carve((size_t)LYR * H * 64 * 64 * 2);
    bf16*  TEb  = (bf16*)carve((size_t)LYR * H * 64 * 192 * 2);
    float* dtAb = (float*)carve((size_t)LYR * H * NH * 2 * 4);
    float* cfb  = (float*)carve((size_t)LYR * H * NH * 2 * 4);
    float* dAQb = (float*)carve((size_t)LYR * H * NH * 2 * 4);
    bf16* wts[5];
    for (int i = 0; i < 5; i++) wts[i] = (bf16*)carve((size_t)LYR * H * H * 2);
    bf16*  Wkf = (bf16*)carve((size_t)LYR * H * H * 2);   // Wk straight bf16
    float* bcb = (float*)carve((size_t)LYR * H * 4);      // combined bias

    bf16*  Yt   = zbA;
    bf16*  bb1  = Ub;                               // Ub dead after conv_p3
    bf16*  bb0  = S0b;                              // S0b dead after conv_p3
    bf16*  bb2  = S0b + (size_t)MROWS * H;          // second half of S0b

    const float* wsrc[5] = {Wk, W1, W2, Wout, Wproj};
    {
        dim3 g(8, 8, LYR);
        for (int i = 0; i < 5; i++)
            cast_w_kernel<<<g, 256, 0, stream>>>(wsrc[i], wts[i], i == 0 ? Wkf : nullptr);
    }
    // Collapse Wk@W1 -> Wct (into wts[0]): Wct[n][m] = sum_k W1t[n][k]*Wkf[m][k]
    wc_gemm<<<dim3(8, 8, LYR), 256, 0, stream>>>(wts[1], Wkf, wts[0]);
    bias_comb_kernel<<<dim3(8, LYR), 256, 0, stream>>>(bk, W1, b1, bcb);

    ssm_params_kernel<<<(LYR * H * NH) / 256, 256, 0, stream>>>(
        logdt, Are, Aim, Bre, Bim, Cre, Cim, dtAb, cfb, dAQb);
    prep_mats<<<LYR * H, 256, 0, stream>>>(dtAb, cfb, Dvec, M1b, TEb);

    const float* cur = x;
    for (int l = 0; l < LYR; l++) {
        ln_trans_k<<<MROWS / 64, 512, 0, stream>>>(cur, ln1w + l * H, ln1b + l * H, Ub);
        conv_p1s<<<H * 4, 256, 0, stream>>>(M1b + (size_t)l * H * 64 * 64, Ub,
                                            dAQb + (size_t)l * H * NH * 2, S0b);
        conv_p3<<<H * 8, 256, 0, stream>>>(TEb + (size_t)l * H * 64 * 192, Ub, S0b, Yt);
        trans_out_k<<<BATCH * NC * 8, 256, 0, stream>>>(Yt, bb0);   // bb0 = y_gelu bf16

        dim3 gg(H / 128, MROWS / 128);
        // o1 = y_gelu @ Wc + bc + out   -> bf16 ONLY (no fp32 round-trip)
        gemm_kernel<M_RES><<<gg, 256, 0, stream>>>(
            bb0, wts[0] + (size_t)l * H * H, nullptr, nullptr,
            bcb + l * H, nullptr, cur, nullptr, bb1, 512);
        // LN2 on bf16 o1 (fp32 stats)
        ln_bf16_kernel<<<MROWS / 4, 256, 0, stream>>>(bb1, ln2w + l * H, ln2b + l * H, bb0);
        gemm_kernel<M_GELU><<<gg, 256, 0, stream>>>(
            bb0, wts[2] + (size_t)l * H * H, nullptr, nullptr,
            b2 + l * H, nullptr, nullptr, nullptr, bb2, 512);
        gemm_kernel<M_DUAL><<<gg, 256, 0, stream>>>(
            bb2, wts[3] + (size_t)l * H * H, bb1, wts[4] + (size_t)l * H * H,
            bout + l * H, bproj + l * H, nullptr, outp, nullptr, 1024);
        cur = outp;
    }
}